// Round 7
// baseline (504.931 us; speedup 1.0000x reference)
//
#include <hip/hip_runtime.h>

typedef unsigned short u16;
typedef unsigned int u32;
typedef __attribute__((ext_vector_type(8))) short vbf8;   // 8 bf16 = 4 VGPR
typedef __attribute__((ext_vector_type(4))) short vs4;    // 4 bf16 = 8 B
typedef __attribute__((ext_vector_type(4))) float vf4;    // MFMA acc / float4

// ---------- bf16 <-> f32 (bitwise; RNE on pack) ----------
__device__ __forceinline__ float b2f(u16 u) {
  union { unsigned int i; float f; } v; v.i = ((unsigned int)u) << 16; return v.f;
}
__device__ __forceinline__ u16 f2b(float f) {
  union { float f; unsigned int i; } v; v.f = f;
  unsigned int r = v.i + 0x7fffu + ((v.i >> 16) & 1u);
  return (u16)(r >> 16);
}
__device__ __forceinline__ u16 f2h(float f) {
  union { _Float16 h; u16 s; } cv; cv.h = (_Float16)f; return cv.s;
}
__device__ __forceinline__ float h2f(u16 u) {
  union { _Float16 h; u16 s; } cv; cv.s = u; return (float)cv.h;
}

// ---------- tiny cross-kernel state ------
__device__ float g_state[512];
#define GS_FEATWN 0      // 256
#define GS_FEATBL 256    // 128
#define GS_W3D    384    // 32
#define GS_BLEND  416    // 4
#define GS_ACCS   420    // 2

// ---------- MFMA-fragment-ordered bf16 conv weights ----------
// conv2..4 frag (kc,t,nt): 64 lanes x 8 bf16;
//   elem (l,j) = W[oc=nt*16+(l&15)][ic=kc*32+(l>>4)*8+j][t]; idx = (kc*9+t)*NTF+nt
// conv1 v2 frag (g,mt): elem (l,j) = W[oc=mt*16+(l&15)][ic=j][tap=g*4+(l>>4)],
//   zero when j>=3 or tap>=9 ; frag idx = g*MT1 + mt (3 groups)
__device__ __align__(16) u16 g_wfrag[92160];
#define WF_WN2 0       // NTF=2 KC=1 : 18 frags
#define WF_BL2 9216    // NTF=1 KC=1 :  9
#define WF_WN3 13824   // NTF=4 KC=1 : 36
#define WF_WN4 32256   // NTF=4 KC=2 : 72
#define WF_BL3 69120   // NTF=2 KC=1 : 18 (I=16 zero-pad)
#define WF_BL4 78336   // NTF=2 KC=1 : 18
#define WF_WN1 87552   // conv1 v2: 3 groups x 2 mt = 6 frags
#define WF_BL1 90624   // conv1 v2: 3 groups x 1 mt = 3 frags

// ---------- output layout (fp32 elements) ----------
#define OUT_FUSED 12582912
#define OUT_TV    13014156
#define OUT_MN    13014157
#define OUT_W3D   13014158

// ---------- prep: pack all conv weights into MFMA fragment order ----------
struct P2Args { const float* w[8]; int I[8]; int ntf[8]; int base[8]; };

__global__ __launch_bounds__(256) void kprep2(P2Args a) {
  if (blockIdx.x == 0 && threadIdx.x < 256) {
    g_state[threadIdx.x] = 0.f;
    if (threadIdx.x < 128) g_state[256 + threadIdx.x] = 0.f;
  }
  int i = blockIdx.x * 256 + threadIdx.x;   // grid 360*256 = 92160 exact
  int l = 0;
  #pragma unroll
  for (int k = 1; k < 8; k++) if (i >= a.base[k]) l = k;
  int e2 = i - a.base[l];
  int frag = e2 >> 9, e = e2 & 511;
  int ll = e >> 3, j = e & 7;
  if (l < 6) {
    int NTF = a.ntf[l];
    int kc = frag / (9 * NTF);
    int r = frag - kc * 9 * NTF;
    int t = r / NTF, nt = r - t * NTF;
    int I = a.I[l];
    int oc = nt * 16 + (ll & 15);
    int ic = kc * 32 + (ll >> 4) * 8 + j;
    g_wfrag[i] = (ic < I) ? f2b(a.w[l][(oc * I + ic) * 9 + t]) : (u16)0;
  } else {
    // conv1 v2: tap-group layout
    int isWN = (l == 6);
    int g = isWN ? (frag >> 1) : frag;
    int mt = isWN ? (frag & 1) : 0;
    int tap = g * 4 + (ll >> 4);
    int oc = mt * 16 + (ll & 15);
    g_wfrag[i] = (j < 3 && tap < 9) ? f2b(a.w[l][oc * 27 + j * 9 + tap]) : (u16)0;
  }
}

// ---------- merged WN+BL conv1+conv2 (ws path), 1024 threads / 16 waves ----------
// LDS ~125 KB -> 1 block/CU, but 16 waves/CU (4/SIMD) for latency hiding.
// x staged once as NHWC [35][36][8]; conv1 B-frags (3x ds_read_b128) shared
// between WN and BL; both h1 buffers resident. One row per wave in conv2.
__global__ __launch_bounds__(1024) void k12d(
    const float* __restrict__ x,
    const float* __restrict__ wb1, const float* __restrict__ wb2,
    const float* __restrict__ bb1, const float* __restrict__ bb2,
    u16* __restrict__ h2w, u16* __restrict__ h2b)
{
  __shared__ __align__(16) u16 xs[10080];      // 35*36*8 = 20,160 B
  __shared__ __align__(16) u16 h1w[35904];     // 2*33*17*32 = 71,808 B
  __shared__ __align__(16) u16 h1b[17952];     // 2*33*17*16 = 35,904 B
  __shared__ __align__(16) u16 zbuf[8];
  const int tid = threadIdx.x;
  const int lane = tid & 63, wv = tid >> 6;    // wv 0..15
  const int ocl = lane & 15;
  const int kg  = lane >> 4;
  const int oy0 = blockIdx.y * 16, ox0 = blockIdx.x * 16;
  const int hy0 = 2 * oy0 - 1, hx0 = 2 * ox0 - 1;
  const float* xb = x + (size_t)blockIdx.z * 3145728u;
  u16* h2wb = h2w + (size_t)blockIdx.z * 262144u * 32u;
  u16* h2bb = h2b + (size_t)blockIdx.z * 262144u * 16u;

  if (tid < 8) zbuf[tid] = 0;
  // ---- stage x NHWC ----
  for (int i = tid; i < 1225; i += 1024) {
    int yy = i / 35, xx = i - yy * 35;
    int gy = hy0 - 1 + yy, gx = hx0 - 1 + xx;
    vbf8 v = {0, 0, 0, 0, 0, 0, 0, 0};
    if ((unsigned)gy < 1024u && (unsigned)gx < 1024u) {
      const float* pp = xb + (gy << 10) + gx;
      v[0] = (short)f2b(pp[0]);
      v[1] = (short)f2b(pp[1048576]);
      v[2] = (short)f2b(pp[2097152]);
    }
    *(vbf8*)(&xs[(yy * 36 + xx) * 8]) = v;
  }

  // per-lane tap-group byte offsets (clamped for pad taps; weights are 0 there)
  int tgo[3];
  #pragma unroll
  for (int g = 0; g < 3; g++) {
    int tap = g * 4 + kg; if (tap > 8) tap = 8;
    tgo[g] = ((tap / 3) * 36 + (tap % 3)) * 16;   // bytes
  }

  // conv1 weight frags + biases
  vbf8 waW[6], waB[3];
  float bias1[2][4], bias1b[4];
  {
    const u16* wfb = g_wfrag + lane * 8;
    #pragma unroll
    for (int q = 0; q < 6; q++) waW[q] = *(const vbf8*)(wfb + WF_WN1 + q * 512);
    #pragma unroll
    for (int g = 0; g < 3; g++) waB[g] = *(const vbf8*)(wfb + WF_BL1 + g * 512);
    #pragma unroll
    for (int j = 0; j < 4; j++) {
      bias1[0][j] = wb1[kg * 4 + j];
      bias1[1][j] = wb1[16 + kg * 4 + j];
      bias1b[j]   = bb1[kg * 4 + j];
    }
  }
  __syncthreads();

  // ---- conv1 (both nets, shared B-frags); 69 tiles over 16 waves ----
  for (int pt = wv; pt < 69; pt += 16) {
    const int p = pt * 16 + ocl;
    const bool ok = (p < 1089);
    const int pc = ok ? p : 1088;
    const int py = pc / 33, px = pc - py * 33;
    const char* pb = (const char*)&xs[(py * 36 + px) * 8];
    vbf8 bf[3];
    #pragma unroll
    for (int g = 0; g < 3; g++)
      bf[g] = *(const vbf8*)(pb + tgo[g]);
    const int par = px & 1, hx = px >> 1;
    // WN
    {
      const int f = (hx >> 1) & 3;
      const int hb = ((par * 33 + py) * 17 + hx) * 32;
      #pragma unroll
      for (int mt = 0; mt < 2; mt++) {
        vf4 acc = {0.f, 0.f, 0.f, 0.f};
        #pragma unroll
        for (int g = 0; g < 3; g++)
          acc = __builtin_amdgcn_mfma_f32_16x16x32_bf16(waW[g * 2 + mt], bf[g], acc, 0, 0, 0);
        if (ok) {
          vs4 pk;
          #pragma unroll
          for (int j = 0; j < 4; j++)
            pk[j] = (short)f2b(fmaxf(acc[j] + bias1[mt][j], 0.f));
          const int q = kg + 4 * mt;
          *(vs4*)(&h1w[hb + ((q >> 1) ^ f) * 8 + (q & 1) * 4]) = pk;
        }
      }
    }
    // BL
    {
      const int f = (hx >> 2) & 1;
      vf4 acc = {0.f, 0.f, 0.f, 0.f};
      #pragma unroll
      for (int g = 0; g < 3; g++)
        acc = __builtin_amdgcn_mfma_f32_16x16x32_bf16(waB[g], bf[g], acc, 0, 0, 0);
      if (ok) {
        vs4 pk;
        #pragma unroll
        for (int j = 0; j < 4; j++)
          pk[j] = (short)f2b(fmaxf(acc[j] + bias1b[j], 0.f));
        *(vs4*)(&h1b[((par * 33 + py) * 17 + hx) * 16 + ((kg >> 1) ^ f) * 8 + (kg & 1) * 4]) = pk;
      }
    }
  }
  __syncthreads();

  // ---- conv2 WN (NT=2, NG=4); one output row per wave ----
  {
    vbf8 bw[18];
    const u16* wfb = g_wfrag + WF_WN2 + lane * 8;
    #pragma unroll
    for (int i = 0; i < 18; i++)
      bw[i] = *(const vbf8*)(wfb + i * 512);

    vf4 acc2[2];
    #pragma unroll
    for (int nt = 0; nt < 2; nt++) {
      float bv = wb2[nt * 16 + ocl];
      vf4 c; c[0] = bv; c[1] = bv; c[2] = bv; c[3] = bv;
      acc2[nt] = c;
    }
    #pragma unroll
    for (int t = 0; t < 9; t++) {
      const int ty = t / 3, tx = t % 3;
      const int par = tx & 1;
      const int hx = (lane & 15) + (tx >> 1);
      const int f = (hx >> 1) & 3;
      const int y = 2 * wv + ty;
      vbf8 a = *(const vbf8*)(&h1w[((par * 33 + y) * 17 + hx) * 32 + ((kg ^ f) & 3) * 8]);
      #pragma unroll
      for (int nt = 0; nt < 2; nt++)
        acc2[nt] = __builtin_amdgcn_mfma_f32_16x16x32_bf16(
            a, bw[t * 2 + nt], acc2[nt], 0, 0, 0);
    }
    const int oy = oy0 + wv;
    #pragma unroll
    for (int nt = 0; nt < 2; nt++)
      #pragma unroll
      for (int j = 0; j < 4; j++) {
        const int ox = ox0 + kg * 4 + j;
        h2wb[((size_t)(oy << 9) + ox) * 32 + nt * 16 + ocl] =
            f2b(fmaxf(acc2[nt][j], 0.f));
      }
  }

  // ---- conv2 BL (NT=1, NG=2); one output row per wave ----
  {
    vbf8 bw[9];
    const u16* wfb = g_wfrag + WF_BL2 + lane * 8;
    #pragma unroll
    for (int i = 0; i < 9; i++)
      bw[i] = *(const vbf8*)(wfb + i * 512);

    vf4 acc2;
    {
      float bv = bb2[ocl];
      acc2[0] = bv; acc2[1] = bv; acc2[2] = bv; acc2[3] = bv;
    }
    #pragma unroll
    for (int t = 0; t < 9; t++) {
      const int ty = t / 3, tx = t % 3;
      const int par = tx & 1;
      const int hx = (lane & 15) + (tx >> 1);
      const int f = (hx >> 2) & 1;
      const int y = 2 * wv + ty;
      const u16* ap = (kg < 2)
          ? &h1b[((par * 33 + y) * 17 + hx) * 16 + ((kg ^ f) & 1) * 8]
          : zbuf;
      vbf8 a = *(const vbf8*)ap;
      acc2 = __builtin_amdgcn_mfma_f32_16x16x32_bf16(a, bw[t], acc2, 0, 0, 0);
    }
    const int oy = oy0 + wv;
    #pragma unroll
    for (int j = 0; j < 4; j++) {
      const int ox = ox0 + kg * 4 + j;
      h2bb[((size_t)(oy << 9) + ox) * 16 + ocl] = f2b(fmaxf(acc2[j], 0.f));
    }
  }
}

// ---------- separate conv1+conv2 (fallback path), 512 threads, v2 conv1 ----------
template<int C1, int C2, int NT, int NG>
__global__ __launch_bounds__(512) void k12m(
    const float* __restrict__ x, int wf1o, const float* __restrict__ b1,
    const float* __restrict__ b2, int wfo, u16* __restrict__ h2)
{
  constexpr int FS = (NG == 4) ? 1 : 2;
  constexpr int MT1 = C1 / 16;
  __shared__ __align__(16) u16 xs[10080];
  __shared__ __align__(16) u16 h1p[2][33][17][C1];
  __shared__ __align__(16) u16 zbuf[8];
  const int tid = threadIdx.x;
  const int lane = tid & 63, wv = tid >> 6;
  const int ocl = lane & 15;
  const int kg  = lane >> 4;
  const int oy0 = blockIdx.y * 16, ox0 = blockIdx.x * 16;
  const int hy0 = 2 * oy0 - 1, hx0 = 2 * ox0 - 1;
  const float* xb = x + (size_t)blockIdx.z * 3145728u;
  u16* h2b = h2 + (size_t)blockIdx.z * 262144u * (size_t)C2;

  if (tid < 8) zbuf[tid] = 0;
  for (int i = tid; i < 1225; i += 512) {
    int yy = i / 35, xx = i - yy * 35;
    int gy = hy0 - 1 + yy, gx = hx0 - 1 + xx;
    vbf8 v = {0, 0, 0, 0, 0, 0, 0, 0};
    if ((unsigned)gy < 1024u && (unsigned)gx < 1024u) {
      const float* pp = xb + (gy << 10) + gx;
      v[0] = (short)f2b(pp[0]);
      v[1] = (short)f2b(pp[1048576]);
      v[2] = (short)f2b(pp[2097152]);
    }
    *(vbf8*)(&xs[(yy * 36 + xx) * 8]) = v;
  }

  int tgo[3];
  #pragma unroll
  for (int g = 0; g < 3; g++) {
    int tap = g * 4 + kg; if (tap > 8) tap = 8;
    tgo[g] = ((tap / 3) * 36 + (tap % 3)) * 16;
  }

  vbf8 wa1[3 * MT1];
  float bias1[MT1][4];
  {
    const u16* wfb = g_wfrag + wf1o + lane * 8;
    #pragma unroll
    for (int q = 0; q < 3 * MT1; q++)
      wa1[q] = *(const vbf8*)(wfb + q * 512);
    #pragma unroll
    for (int mt = 0; mt < MT1; mt++)
      #pragma unroll
      for (int j = 0; j < 4; j++)
        bias1[mt][j] = b1[mt * 16 + kg * 4 + j];
  }
  __syncthreads();

  for (int pt = wv; pt < 69; pt += 8) {
    const int p = pt * 16 + ocl;
    const bool ok = (p < 1089);
    const int pc = ok ? p : 1088;
    const int py = pc / 33, px = pc - py * 33;
    const char* pb = (const char*)&xs[(py * 36 + px) * 8];
    vbf8 bf[3];
    #pragma unroll
    for (int g = 0; g < 3; g++)
      bf[g] = *(const vbf8*)(pb + tgo[g]);
    const int par = px & 1, hx = px >> 1;
    const int f = (hx >> FS) & (NG - 1);
    #pragma unroll
    for (int mt = 0; mt < MT1; mt++) {
      vf4 acc = {0.f, 0.f, 0.f, 0.f};
      #pragma unroll
      for (int g = 0; g < 3; g++)
        acc = __builtin_amdgcn_mfma_f32_16x16x32_bf16(wa1[g * MT1 + mt], bf[g], acc, 0, 0, 0);
      if (ok) {
        vs4 pk;
        #pragma unroll
        for (int j = 0; j < 4; j++)
          pk[j] = (short)f2b(fmaxf(acc[j] + bias1[mt][j], 0.f));
        const int q = kg + 4 * mt;
        *(vs4*)(&h1p[par][py][hx][((q >> 1) ^ f) * 8 + (q & 1) * 4]) = pk;
      }
    }
  }
  __syncthreads();

  vbf8 bw[9 * NT];
  {
    const u16* wfb = g_wfrag + wfo + lane * 8;
    #pragma unroll
    for (int i = 0; i < 9 * NT; i++)
      bw[i] = *(const vbf8*)(wfb + i * 512);
  }

  vf4 acc2[2][NT];
  #pragma unroll
  for (int nt = 0; nt < NT; nt++) {
    float bv = b2[nt * 16 + ocl];
    #pragma unroll
    for (int mt = 0; mt < 2; mt++) {
      vf4 c; c[0] = bv; c[1] = bv; c[2] = bv; c[3] = bv;
      acc2[mt][nt] = c;
    }
  }

  #pragma unroll
  for (int t = 0; t < 9; t++) {
    const int ty = t / 3, tx = t % 3;
    const int par = tx & 1;
    const int hx = (lane & 15) + (tx >> 1);
    const int f = (hx >> FS) & (NG - 1);
    #pragma unroll
    for (int mt = 0; mt < 2; mt++) {
      const int y = 2 * (wv * 2 + mt) + ty;
      const u16* ap;
      if constexpr (NG == 4) {
        ap = &h1p[par][y][hx][((kg ^ f) & 3) * 8];
      } else {
        ap = (kg < NG) ? &h1p[par][y][hx][((kg ^ f) & (NG - 1)) * 8] : zbuf;
      }
      vbf8 a = *(const vbf8*)ap;
      #pragma unroll
      for (int nt = 0; nt < NT; nt++)
        acc2[mt][nt] = __builtin_amdgcn_mfma_f32_16x16x32_bf16(
            a, bw[t * NT + nt], acc2[mt][nt], 0, 0, 0);
    }
  }

  #pragma unroll
  for (int mt = 0; mt < 2; mt++) {
    const int oy = oy0 + wv * 2 + mt;
    #pragma unroll
    for (int nt = 0; nt < NT; nt++) {
      #pragma unroll
      for (int j = 0; j < 4; j++) {
        const int ox = ox0 + kg * 4 + j;
        h2b[((size_t)(oy << 9) + ox) * C2 + nt * 16 + ocl] =
            f2b(fmaxf(acc2[mt][nt][j], 0.f));
      }
    }
  }
}

// ---------- stride-2 conv on MFMA (conv3/conv4), NHWC in, 512 threads ----------
template<int CIN, int COUT, int NT, int NG, int KC, bool REDUCE>
__global__ __launch_bounds__(512) void k34m(
    const u16* __restrict__ in, const float* __restrict__ bia,
    int wfo, u16* __restrict__ out, int HIN, int gofs)
{
  constexpr int FS = (NG == 4) ? 1 : 2;
  constexpr int NTF = COUT / 16;
  constexpr int OCG = COUT / (NT * 16);
  __shared__ __align__(16) u16 h1p[2][33][17][NG * 8];
  __shared__ __align__(16) u16 zbuf[8];
  __shared__ float rsum[NT * 16];
  const int HO = HIN >> 1;
  const int tid = threadIdx.x;
  const int lane = tid & 63, wv = tid >> 6;
  const int zb2 = blockIdx.z / OCG;
  const int og = blockIdx.z - zb2 * OCG;
  const int oy0 = blockIdx.y * 16, ox0 = blockIdx.x * 16;
  const int iy0 = 2 * oy0 - 1, ix0 = 2 * ox0 - 1;
  const u16* inb = in + (size_t)zb2 * (size_t)HIN * HIN * CIN;

  if (tid < 8) zbuf[tid] = 0;
  if (REDUCE && tid < NT * 16) rsum[tid] = 0.f;

  const int ocl = lane & 15;
  const int kg  = lane >> 4;

  vf4 acc2[2][NT];
  #pragma unroll
  for (int nt = 0; nt < NT; nt++) {
    float bv = bia[og * NT * 16 + nt * 16 + ocl];
    #pragma unroll
    for (int mt = 0; mt < 2; mt++) {
      vf4 c; c[0] = bv; c[1] = bv; c[2] = bv; c[3] = bv;
      acc2[mt][nt] = c;
    }
  }

  vbf8 bw[9 * NT];

  for (int kc = 0; kc < KC; kc++) {
    if (kc) __syncthreads();
    for (int i = tid; i < 33 * 33 * NG; i += 512) {
      int g = i & (NG - 1);
      int pp = i / NG;
      int yy = pp / 33, xx = pp - yy * 33;
      int gy = iy0 + yy, gx = ix0 + xx;
      vbf8 v = {0, 0, 0, 0, 0, 0, 0, 0};
      if ((unsigned)gy < (unsigned)HIN && (unsigned)gx < (unsigned)HIN)
        v = *(const vbf8*)(inb + (size_t)(gy * HIN + gx) * CIN + kc * 32 + g * 8);
      const int par = xx & 1, hx = xx >> 1;
      const int f = (hx >> FS) & (NG - 1);
      *(vbf8*)(&h1p[par][yy][hx][(g ^ f) * 8]) = v;
    }
    {
      const u16* wfb = g_wfrag + wfo + lane * 8;
      #pragma unroll
      for (int t = 0; t < 9; t++)
        #pragma unroll
        for (int nt = 0; nt < NT; nt++)
          bw[t * NT + nt] =
              *(const vbf8*)(wfb + (size_t)((kc * 9 + t) * NTF + og * NT + nt) * 512);
    }
    __syncthreads();

    #pragma unroll
    for (int t = 0; t < 9; t++) {
      const int ty = t / 3, tx = t % 3;
      const int par = tx & 1;
      const int hx = (lane & 15) + (tx >> 1);
      const int f = (hx >> FS) & (NG - 1);
      #pragma unroll
      for (int mt = 0; mt < 2; mt++) {
        const int y = 2 * (wv * 2 + mt) + ty;
        const u16* ap;
        if constexpr (NG == 4) {
          ap = &h1p[par][y][hx][((kg ^ f) & 3) * 8];
        } else {
          ap = (kg < NG) ? &h1p[par][y][hx][((kg ^ f) & (NG - 1)) * 8] : zbuf;
        }
        vbf8 a = *(const vbf8*)ap;
        #pragma unroll
        for (int nt = 0; nt < NT; nt++)
          acc2[mt][nt] = __builtin_amdgcn_mfma_f32_16x16x32_bf16(
              a, bw[t * NT + nt], acc2[mt][nt], 0, 0, 0);
      }
    }
  }

  if constexpr (REDUCE) {
    #pragma unroll
    for (int nt = 0; nt < NT; nt++) {
      float part = 0.f;
      #pragma unroll
      for (int mt = 0; mt < 2; mt++)
        #pragma unroll
        for (int j = 0; j < 4; j++)
          part += fmaxf(acc2[mt][nt][j], 0.f);
      atomicAdd(&rsum[nt * 16 + ocl], part);
    }
    __syncthreads();
    if (tid < NT * 16)
      atomicAdd(&g_state[gofs + zb2 * COUT + og * NT * 16 + tid],
                rsum[tid] * (1.f / 16384.f));
  } else {
    #pragma unroll
    for (int mt = 0; mt < 2; mt++) {
      const int oy = oy0 + wv * 2 + mt;
      #pragma unroll
      for (int nt = 0; nt < NT; nt++) {
        const int oc = og * NT * 16 + nt * 16 + ocl;
        #pragma unroll
        for (int j = 0; j < 4; j++) {
          const int ox = ox0 + kg * 4 + j;
          out[((size_t)zb2 * HO * HO + (size_t)(oy * HO + ox)) * COUT + oc] =
              f2b(fmaxf(acc2[mt][nt][j], 0.f));
        }
      }
    }
  }
}

// ---------- FC head ----------
template<int CF, int NOUT, bool SIG>
__global__ __launch_bounds__(256) void khead(
    const float* __restrict__ fw1, const float* __restrict__ fb1,
    const float* __restrict__ fw2, const float* __restrict__ fb2,
    int feato, int outo, float* out_f)
{
  __shared__ float fc1[4 * CF];
  const int tid = threadIdx.x;
  if (tid < 4 * CF) {
    int b = tid / CF, o = tid - b * CF;
    float s = fb1[o];
    for (int i = 0; i < CF; i++)
      s = fmaf(g_state[feato + b * CF + i], fw1[o * CF + i], s);
    fc1[tid] = fmaxf(s, 0.f);
  }
  __syncthreads();
  if (tid < 4 * NOUT) {
    int b = tid / NOUT, n = tid - b * NOUT;
    float s = fb2[n];
    for (int i = 0; i < CF; i++)
      s = fmaf(fc1[b * CF + i], fw2[n * CF + i], s);
    if (SIG) s = 1.f / (1.f + expf(-s));
    g_state[outo + b * NOUT + n] = s;
    if (out_f) out_f[b * NOUT + n] = s;
  }
}

// ---------- fused LUT = clip(w3d @ luts + identity, 0,1); also fp16 AoS copy ----------
__global__ __launch_bounds__(256) void kfuse(
    const float* __restrict__ luts, float* __restrict__ outF,
    u16* __restrict__ Fa)
{
  if (blockIdx.x == 0 && threadIdx.x == 0) {
    g_state[GS_ACCS] = 0.f; g_state[GS_ACCS + 1] = 0.f;
  }
  int idx = blockIdx.x * 256 + threadIdx.x;
  if (idx >= 431244) return;
  int n = idx / 107811, m = idx - n * 107811;
  int c = m / 35937, q = m - c * 35937;
  int bq = q / 1089, r2 = q - bq * 1089;
  int gq = r2 / 33, rq = r2 - gq * 33;
  int id = (c == 0) ? rq : (c == 1) ? gq : bq;
  float s = (float)id * (1.f / 32.f);
  #pragma unroll
  for (int k = 0; k < 8; k++)
    s = fmaf(g_state[GS_W3D + n * 8 + k], luts[k * 107811 + m], s);
  s = fminf(fmaxf(s, 0.f), 1.f);
  outF[idx] = s;
  if (Fa) Fa[(n * 35937 + q) * 4 + c] = f2h(s);
}

// ---------- TV + monotonicity reductions over fused ----------
__global__ __launch_bounds__(256) void ktv(const float* __restrict__ f) {
  const int Nr = 418176;
  float tv = 0.f, mn = 0.f;
  for (int e = blockIdx.x * 256 + threadIdx.x; e < 3 * Nr; e += gridDim.x * 256) {
    int dir = e / Nr, j = e - dir * Nr;
    int i, stride; float w;
    if (dir == 0) {
      int r = j & 31; int t = j >> 5;
      int g = t % 33; t /= 33;
      i = t * 1089 + g * 33 + r; stride = 1;
      w = (r == 0 || r == 31) ? 2.f : 1.f;
    } else if (dir == 1) {
      int r = j % 33; int t = j / 33; int g = t & 31; t >>= 5;
      i = t * 1089 + g * 33 + r; stride = 33;
      w = (g == 0 || g == 31) ? 2.f : 1.f;
    } else {
      int r = j % 33; int t = j / 33; int g = t % 33; t /= 33;
      int bb = t & 31; t >>= 5;
      i = (t * 33 + bb) * 1089 + g * 33 + r; stride = 1089;
      w = (bb == 0 || bb == 31) ? 2.f : 1.f;
    }
    float d = f[i] - f[i + stride];
    tv = fmaf(d * d, w, tv);
    mn += fmaxf(d, 0.f);
  }
  __shared__ float r1[256], r2[256];
  r1[threadIdx.x] = tv; r2[threadIdx.x] = mn; __syncthreads();
  for (int st = 128; st > 0; st >>= 1) {
    if (threadIdx.x < st) { r1[threadIdx.x] += r1[threadIdx.x + st];
                            r2[threadIdx.x] += r2[threadIdx.x + st]; }
    __syncthreads();
  }
  if (threadIdx.x == 0) {
    atomicAdd(&g_state[GS_ACCS], r1[0]);
    atomicAdd(&g_state[GS_ACCS + 1], r2[0]);
  }
}

// ---------- trilinear apply, 4 px/thread, fp16 AoS LUT ----------
__global__ __launch_bounds__(256) void kapply4(
    const float* __restrict__ x, const u16* __restrict__ Fa,
    float* __restrict__ out)
{
  int p = blockIdx.x * 256 + threadIdx.x;   // grid 4096
  if (p == 0) {
    out[OUT_TV] = g_state[GS_ACCS] * (1.f / 418176.f);
    out[OUT_MN] = g_state[GS_ACCS + 1] * (1.f / 418176.f);
  }
  const int b = p >> 18;
  const int yx0 = (p & 262143) * 4;
  const size_t base = (size_t)b * 3145728u + yx0;
  vf4 xr = *(const vf4*)(x + base);
  vf4 xg = *(const vf4*)(x + base + 1048576);
  vf4 xb = *(const vf4*)(x + base + 2097152);
  const float a = g_state[GS_BLEND + b];
  const u32* Fu = (const u32*)Fa;

  int cb4[4];
  float fr4[4], fg4[4], fb4[4];
  #pragma unroll
  for (int i = 0; i < 4; i++) {
    float sr = fminf(fmaxf(xr[i], 0.f), 1.f) * 32.f;
    float sg = fminf(fmaxf(xg[i], 0.f), 1.f) * 32.f;
    float sb = fminf(fmaxf(xb[i], 0.f), 1.f) * 32.f;
    int ir = min((int)sr, 31), ig = min((int)sg, 31), ib = min((int)sb, 31);
    fr4[i] = sr - ir; fg4[i] = sg - ig; fb4[i] = sb - ib;
    cb4[i] = b * 35937 + ib * 1089 + ig * 33 + ir;
  }

  u32 q[4][4][4];
  const int off[4] = {0, 33, 1089, 1122};
  #pragma unroll
  for (int i = 0; i < 4; i++)
    #pragma unroll
    for (int pr = 0; pr < 4; pr++) {
      const u32* c0 = Fu + (size_t)(cb4[i] + off[pr]) * 2;
      q[i][pr][0] = c0[0]; q[i][pr][1] = c0[1];
      q[i][pr][2] = c0[2]; q[i][pr][3] = c0[3];
    }

  vf4 o0, o1, o2;
  #pragma unroll
  for (int i = 0; i < 4; i++) {
    const float fr = fr4[i], fg = fg4[i], fb = fb4[i];
    #pragma unroll
    for (int c = 0; c < 3; c++) {
      const int k = c >> 1, sh = (c & 1) * 16;
      float v000 = h2f((u16)(q[i][0][k]     >> sh));
      float v001 = h2f((u16)(q[i][0][2 + k] >> sh));
      float v010 = h2f((u16)(q[i][1][k]     >> sh));
      float v011 = h2f((u16)(q[i][1][2 + k] >> sh));
      float v100 = h2f((u16)(q[i][2][k]     >> sh));
      float v101 = h2f((u16)(q[i][2][2 + k] >> sh));
      float v110 = h2f((u16)(q[i][3][k]     >> sh));
      float v111 = h2f((u16)(q[i][3][2 + k] >> sh));
      float c00 = v000 + fr * (v001 - v000);
      float c01 = v010 + fr * (v011 - v010);
      float c10 = v100 + fr * (v101 - v100);
      float c11 = v110 + fr * (v111 - v110);
      float c0 = c00 + fg * (c01 - c00);
      float c1 = c10 + fg * (c11 - c10);
      float v  = c0 + fb * (c1 - c0);
      float xv = (c == 0) ? xr[i] : (c == 1) ? xg[i] : xb[i];
      float o = fminf(fmaxf((1.f - a) * xv + a * v, 0.f), 1.f);
      if (c == 0) o0[i] = o; else if (c == 1) o1[i] = o; else o2[i] = o;
    }
  }
  *(vf4*)(out + (size_t)(b * 3 + 0) * 1048576u + yx0) = o0;
  *(vf4*)(out + (size_t)(b * 3 + 1) * 1048576u + yx0) = o1;
  *(vf4*)(out + (size_t)(b * 3 + 2) * 1048576u + yx0) = o2;
}

// ---------- trilinear apply, fallback 1 px/thread, fp32 SoA ----------
__global__ __launch_bounds__(256) void kapply1(
    const float* __restrict__ x, const float* __restrict__ F,
    float* __restrict__ out)
{
  int p = blockIdx.x * 256 + threadIdx.x;
  if (p == 0) {
    out[OUT_TV] = g_state[GS_ACCS] * (1.f / 418176.f);
    out[OUT_MN] = g_state[GS_ACCS + 1] * (1.f / 418176.f);
  }
  int b = p >> 20, yx = p & 1048575;
  size_t base = (size_t)b * 3145728u + yx;
  float xr = x[base];
  float xg = x[base + 1048576];
  float xb = x[base + 2097152];
  float a = g_state[GS_BLEND + b];
  float sr = fminf(fmaxf(xr, 0.f), 1.f) * 32.f;
  float sg = fminf(fmaxf(xg, 0.f), 1.f) * 32.f;
  float sb = fminf(fmaxf(xb, 0.f), 1.f) * 32.f;
  int ir = min((int)sr, 31), ig = min((int)sg, 31), ib = min((int)sb, 31);
  float fr = sr - ir, fg = sg - ig, fb = sb - ib;
  const float* Fb = F + (size_t)b * 107811u + ib * 1089 + ig * 33 + ir;
  #pragma unroll
  for (int c = 0; c < 3; c++) {
    const float* Fc = Fb + c * 35937;
    float v000 = Fc[0],    v001 = Fc[1];
    float v010 = Fc[33],   v011 = Fc[34];
    float v100 = Fc[1089], v101 = Fc[1090];
    float v110 = Fc[1122], v111 = Fc[1123];
    float c00 = v000 + fr * (v001 - v000);
    float c01 = v010 + fr * (v011 - v010);
    float c10 = v100 + fr * (v101 - v100);
    float c11 = v110 + fr * (v111 - v110);
    float c0 = c00 + fg * (c01 - c00);
    float c1 = c10 + fg * (c11 - c10);
    float v  = c0 + fb * (c1 - c0);
    float xv = (c == 0) ? xr : (c == 1) ? xg : xb;
    float o = fminf(fmaxf((1.f - a) * xv + a * v, 0.f), 1.f);
    out[(size_t)(b * 3 + c) * 1048576u + yx] = o;
  }
}

extern "C" void kernel_launch(void* const* d_in, const int* in_sizes, int n_in,
                              void* d_out, int out_size, void* d_ws, size_t ws_size,
                              hipStream_t stream)
{
  (void)in_sizes; (void)n_in; (void)out_size;
  const float* x    = (const float*)d_in[0];
  const float* luts = (const float*)d_in[1];
  const float* wn_b1 = (const float*)d_in[3];
  const float* wn_b2 = (const float*)d_in[5];
  const float* wn_b3 = (const float*)d_in[7];
  const float* wn_b4 = (const float*)d_in[9];
  const float* wn_fw1 = (const float*)d_in[10], *wn_fb1 = (const float*)d_in[11];
  const float* wn_fw2 = (const float*)d_in[12], *wn_fb2 = (const float*)d_in[13];
  const float* bl_b1 = (const float*)d_in[15];
  const float* bl_b2 = (const float*)d_in[17];
  const float* bl_b3 = (const float*)d_in[19];
  const float* bl_b4 = (const float*)d_in[21];
  const float* bl_fw1 = (const float*)d_in[22], *bl_fb1 = (const float*)d_in[23];
  const float* bl_fw2 = (const float*)d_in[24], *bl_fb2 = (const float*)d_in[25];
  float* out = (float*)d_out;
  const bool hasWs = (ws_size >= 50331648u);

  P2Args p2;
  const float* wsrc[8] = {(const float*)d_in[4],  (const float*)d_in[16],
                          (const float*)d_in[6],  (const float*)d_in[8],
                          (const float*)d_in[18], (const float*)d_in[20],
                          (const float*)d_in[2],  (const float*)d_in[14]};
  const int pI[8]   = {32, 16, 32, 64, 16, 32, 3, 3};
  const int pNTF[8] = {2, 1, 4, 4, 2, 2, 2, 1};
  const int pB[8]   = {WF_WN2, WF_BL2, WF_WN3, WF_WN4, WF_BL3, WF_BL4,
                       WF_WN1, WF_BL1};
  for (int l = 0; l < 8; l++) { p2.w[l] = wsrc[l]; p2.I[l] = pI[l];
                                p2.ntf[l] = pNTF[l]; p2.base[l] = pB[l]; }
  kprep2<<<dim3(360), 256, 0, stream>>>(p2);

  if (hasWs) {
    u16* scrA = (u16*)d_ws;                    // WN h2: 33.6 MB
    u16* scrB = (u16*)d_ws + 16777216;         // conv3 out: up to 16.8 MB
    u16* blh2 = (u16*)out;                     // BL h2: 16.8 MB (out scratch)
    u16* Fa   = (u16*)d_ws;                    // fp16 AoS LUT (post-conv)

    for (int b0 = 0; b0 < 4; b0 += 2) {
      const float* xb = x + (size_t)b0 * 3145728u;
      k12d<<<dim3(32,32,2), 1024, 0, stream>>>(xb, wn_b1, wn_b2, bl_b1, bl_b2,
                                               scrA, blh2);
      k34m<32,64,2,4,1,false><<<dim3(16,16,4), 512, 0, stream>>>(scrA, wn_b3, WF_WN3, scrB, 512, 0);
      k34m<64,64,2,4,2,true ><<<dim3(8,8,4),   512, 0, stream>>>(scrB, wn_b4, WF_WN4, nullptr, 256, GS_FEATWN + b0 * 64);
      k34m<16,32,2,2,1,false><<<dim3(16,16,2), 512, 0, stream>>>(blh2, bl_b3, WF_BL3, scrB, 512, 0);
      k34m<32,32,2,4,1,true ><<<dim3(8,8,2),   512, 0, stream>>>(scrB, bl_b4, WF_BL4, nullptr, 256, GS_FEATBL + b0 * 32);
    }
    khead<64,8,false><<<1,256,0,stream>>>(wn_fw1, wn_fb1, wn_fw2, wn_fb2,
                                          GS_FEATWN, GS_W3D, out + OUT_W3D);
    khead<32,1,true ><<<1,256,0,stream>>>(bl_fw1, bl_fb1, bl_fw2, bl_fb2,
                                          GS_FEATBL, GS_BLEND, (float*)nullptr);

    kfuse<<<1685, 256, 0, stream>>>(luts, out + OUT_FUSED, Fa);
    ktv<<<512, 256, 0, stream>>>(out + OUT_FUSED);
    kapply4<<<4096, 256, 0, stream>>>(x, Fa, out);
  } else {
    u16* scrA = (u16*)out;
    u16* scrB = (u16*)out + 16777216;

    for (int b0 = 0; b0 < 4; b0 += 2) {
      const float* xb = x + (size_t)b0 * 3145728u;
      k12m<32,32,2,4><<<dim3(32,32,2), 512, 0, stream>>>(xb, WF_WN1, wn_b1, wn_b2, WF_WN2, scrA);
      k34m<32,64,2,4,1,false><<<dim3(16,16,4), 512, 0, stream>>>(scrA, wn_b3, WF_WN3, scrB, 512, 0);
      k34m<64,64,2,4,2,true ><<<dim3(8,8,4),   512, 0, stream>>>(scrB, wn_b4, WF_WN4, nullptr, 256, GS_FEATWN + b0 * 64);
    }
    khead<64,8,false><<<1,256,0,stream>>>(wn_fw1, wn_fb1, wn_fw2, wn_fb2,
                                          GS_FEATWN, GS_W3D, out + OUT_W3D);
    for (int b0 = 0; b0 < 4; b0 += 2) {
      const float* xb = x + (size_t)b0 * 3145728u;
      k12m<16,16,1,2><<<dim3(32,32,2), 512, 0, stream>>>(xb, WF_BL1, bl_b1, bl_b2, WF_BL2, scrA);
      k34m<16,32,2,2,1,false><<<dim3(16,16,2), 512, 0, stream>>>(scrA, bl_b3, WF_BL3, scrB, 512, 0);
      k34m<32,32,2,4,1,true ><<<dim3(8,8,2),   512, 0, stream>>>(scrB, bl_b4, WF_BL4, nullptr, 256, GS_FEATBL + b0 * 32);
    }
    khead<32,1,true ><<<1,256,0,stream>>>(bl_fw1, bl_fb1, bl_fw2, bl_fb2,
                                          GS_FEATBL, GS_BLEND, (float*)nullptr);

    kfuse<<<1685, 256, 0, stream>>>(luts, out + OUT_FUSED, nullptr);
    ktv<<<512, 256, 0, stream>>>(out + OUT_FUSED);
    kapply1<<<16384, 256, 0, stream>>>(x, out + OUT_FUSED, out);
  }
}

// Round 8
// 480.620 us; speedup vs baseline: 1.0506x; 1.0506x over previous
//
#include <hip/hip_runtime.h>

typedef unsigned short u16;
typedef unsigned int u32;
typedef __attribute__((ext_vector_type(8))) short vbf8;   // 8 bf16 = 4 VGPR
typedef __attribute__((ext_vector_type(4))) short vs4;    // 4 bf16 = 8 B
typedef __attribute__((ext_vector_type(4))) float vf4;    // MFMA acc / float4

// ---------- bf16 <-> f32 (bitwise; RNE on pack) ----------
__device__ __forceinline__ float b2f(u16 u) {
  union { unsigned int i; float f; } v; v.i = ((unsigned int)u) << 16; return v.f;
}
__device__ __forceinline__ u16 f2b(float f) {
  union { float f; unsigned int i; } v; v.f = f;
  unsigned int r = v.i + 0x7fffu + ((v.i >> 16) & 1u);
  return (u16)(r >> 16);
}
__device__ __forceinline__ u16 f2h(float f) {
  union { _Float16 h; u16 s; } cv; cv.h = (_Float16)f; return cv.s;
}
__device__ __forceinline__ float h2f(u16 u) {
  union { _Float16 h; u16 s; } cv; cv.s = u; return (float)cv.h;
}
// two 8B LDS reads -> one bf16x8 fragment (8B-aligned safe)
__device__ __forceinline__ vbf8 ldpair(const u16* p) {
  vs4 lo = *(const vs4*)p;
  vs4 hi = *(const vs4*)(p + 4);
  return __builtin_shufflevector(lo, hi, 0, 1, 2, 3, 4, 5, 6, 7);
}

// ---------- tiny cross-kernel state ------
__device__ float g_state[512];
#define GS_FEATWN 0      // 256
#define GS_FEATBL 256    // 128
#define GS_W3D    384    // 32
#define GS_BLEND  416    // 4
#define GS_ACCS   420    // 2

// ---------- MFMA-fragment-ordered bf16 conv weights ----------
// conv2 WN (halfK): 2 variants x 9 taps x 2 nt; variant c holds ic=c*16+k (k<16), upper-K zero.
// conv2 BL / conv3 / conv4: elem (l,j) = W[oc=nt*16+(l&15)][ic=kc*C+(l>>4)*8+j][t], zero-pad.
// conv1 tap-pair: k = kg*8 + tp*4 + ic; tap = PAIR[g*4+kg][tp]; pairs
//   {0,1},{3,4},{6,7},{2,-},{5,-},{8,-}; ic>=3 or dead tap -> 0.
__device__ __align__(16) u16 g_wfrag[99840];
#define WF_WN2 0       // 36 frags (2 halfK variants)
#define WF_BL2 18432   //  9
#define WF_WN3 23040   // 36
#define WF_WN4 41472   // 72
#define WF_BL3 78336   // 18 (I=16 zero-pad)
#define WF_BL4 87552   // 18
#define WF_WN1 96768   //  4 (2 oc-chunks x 2 groups)
#define WF_BL1 98816   //  2

// ---------- output layout (fp32 elements) ----------
#define OUT_FUSED 12582912
#define OUT_TV    13014156
#define OUT_MN    13014157
#define OUT_W3D   13014158

// ---------- prep: pack all conv weights into MFMA fragment order ----------
struct P2Args { const float* w[8]; int I[8]; int ntf[8]; int base[8]; int halfk[8]; };

__global__ __launch_bounds__(256) void kprep2(P2Args a) {
  if (blockIdx.x == 0 && threadIdx.x < 256) {
    g_state[threadIdx.x] = 0.f;
    if (threadIdx.x < 128) g_state[256 + threadIdx.x] = 0.f;
  }
  int i = blockIdx.x * 256 + threadIdx.x;   // grid 390*256 = 99840 exact
  int l = 0;
  #pragma unroll
  for (int k = 1; k < 8; k++) if (i >= a.base[k]) l = k;
  int e2 = i - a.base[l];
  int frag = e2 >> 9, e = e2 & 511;
  int ll = e >> 3, j = e & 7;
  if (l < 6) {
    int NTF = a.ntf[l];
    int kc = frag / (9 * NTF);
    int r = frag - kc * 9 * NTF;
    int t = r / NTF, nt = r - t * NTF;
    int I = a.I[l];
    int oc = nt * 16 + (ll & 15);
    int kk = (ll >> 4) * 8 + j;
    u16 v = 0;
    if (a.halfk[l]) {
      int ic = kc * 16 + kk;
      if (kk < 16 && ic < I) v = f2b(a.w[l][(oc * I + ic) * 9 + t]);
    } else {
      int ic = kc * 32 + kk;
      if (ic < I) v = f2b(a.w[l][(oc * I + ic) * 9 + t]);
    }
    g_wfrag[i] = v;
  } else {
    // conv1 tap-pair packing
    int isWN = (l == 6);
    int c2 = isWN ? (frag >> 1) : 0;
    int g = isWN ? (frag & 1) : frag;
    int idx = g * 4 + (ll >> 4);
    int tp = j >> 2, ic = j & 3;
    int tap = (tp == 0)
        ? ((idx == 0) ? 0 : (idx == 1) ? 3 : (idx == 2) ? 6 :
           (idx == 3) ? 2 : (idx == 4) ? 5 : (idx == 5) ? 8 : -1)
        : ((idx == 0) ? 1 : (idx == 1) ? 4 : (idx == 2) ? 7 : -1);
    int oc = c2 * 16 + (ll & 15);
    g_wfrag[i] = (ic < 3 && tap >= 0) ? f2b(a.w[l][oc * 27 + ic * 9 + tap]) : (u16)0;
  }
}

// ---------- merged WN+BL conv1+conv2, 512 thr / 8 waves, 46 KB LDS ----------
// 2 blocks/CU (cross-block barrier overlap). One 16-ch h1 time-shared by 3
// K-chunks: WN oc0-15, WN oc16-31 (half-K conv2 variants), then BL.
__global__ __launch_bounds__(512, 4) void k12d(
    const float* __restrict__ x,
    const float* __restrict__ wb1, const float* __restrict__ wb2,
    const float* __restrict__ bb1, const float* __restrict__ bb2,
    u16* __restrict__ h2w, u16* __restrict__ h2b)
{
  __shared__ __align__(16) u16 xs4[5056];   // [35][36][4] + pad = 10,112 B
  __shared__ __align__(16) u16 h1[17952];   // [2][33][17][16] = 35,904 B
  const int tid = threadIdx.x;
  const int lane = tid & 63, wv = tid >> 6;
  const int ocl = lane & 15;
  const int kg  = lane >> 4;
  const int oy0 = blockIdx.y * 16, ox0 = blockIdx.x * 16;
  const int hy0 = 2 * oy0 - 1, hx0 = 2 * ox0 - 1;
  const float* xb = x + (size_t)blockIdx.z * 3145728u;
  u16* h2wb = h2w + (size_t)blockIdx.z * 8388608u;
  u16* h2bb = h2b + (size_t)blockIdx.z * 4194304u;

  // ---- stage x as 4-ch NHWC bf16 ----
  for (int i = tid; i < 1225; i += 512) {
    int yy = i / 35, xx = i - yy * 35;
    int gy = hy0 - 1 + yy, gx = hx0 - 1 + xx;
    vs4 v = {0, 0, 0, 0};
    if ((unsigned)gy < 1024u && (unsigned)gx < 1024u) {
      const float* pp = xb + (gy << 10) + gx;
      v[0] = (short)f2b(pp[0]);
      v[1] = (short)f2b(pp[1048576]);
      v[2] = (short)f2b(pp[2097152]);
    }
    *(vs4*)(&xs4[(yy * 36 + xx) * 4]) = v;
  }

  // tap-pair B-frag u16 offsets: group0 start taps {0,3,6,2}, group1 {5,8,d,d}
  const int to0 = (kg < 3 ? kg * 36 : 2) * 4;
  const int to1 = (kg == 0 ? 38 : 74) * 4;

  // WN conv2 accumulators (persist across both K-chunks)
  vf4 accW[2][2];
  #pragma unroll
  for (int nt = 0; nt < 2; nt++) {
    float bv = wb2[nt * 16 + ocl];
    vf4 cc; cc[0] = bv; cc[1] = bv; cc[2] = bv; cc[3] = bv;
    accW[0][nt] = cc; accW[1][nt] = cc;
  }
  __syncthreads();

  #pragma unroll
  for (int c = 0; c < 2; c++) {
    // ---- conv1: WN oc-chunk c ----
    {
      vbf8 wa0 = *(const vbf8*)(g_wfrag + WF_WN1 + (c * 2 + 0) * 512 + lane * 8);
      vbf8 wa1 = *(const vbf8*)(g_wfrag + WF_WN1 + (c * 2 + 1) * 512 + lane * 8);
      float bias[4];
      #pragma unroll
      for (int j = 0; j < 4; j++) bias[j] = wb1[c * 16 + kg * 4 + j];
      for (int pt = wv; pt < 69; pt += 8) {
        const int p = pt * 16 + ocl;
        const bool ok = (p < 1089);
        const int pc = ok ? p : 1088;
        const int py = pc / 33, px = pc - py * 33;
        const u16* pb = xs4 + (py * 36 + px) * 4;
        vbf8 b0 = ldpair(pb + to0);
        vbf8 b1 = ldpair(pb + to1);
        vf4 acc = {0.f, 0.f, 0.f, 0.f};
        acc = __builtin_amdgcn_mfma_f32_16x16x32_bf16(wa0, b0, acc, 0, 0, 0);
        acc = __builtin_amdgcn_mfma_f32_16x16x32_bf16(wa1, b1, acc, 0, 0, 0);
        if (ok) {
          vs4 pk;
          #pragma unroll
          for (int j = 0; j < 4; j++)
            pk[j] = (short)f2b(fmaxf(acc[j] + bias[j], 0.f));
          const int par = px & 1, hx = px >> 1, f = (hx >> 2) & 1;
          *(vs4*)(&h1[((par * 33 + py) * 17 + hx) * 16 + ((kg >> 1) ^ f) * 8 + (kg & 1) * 4]) = pk;
        }
      }
    }
    __syncthreads();
    // ---- conv2: WN half-K variant c ----
    {
      vbf8 bw[18];
      const u16* wfb = g_wfrag + WF_WN2 + c * 18 * 512 + lane * 8;
      #pragma unroll
      for (int i = 0; i < 18; i++)
        bw[i] = *(const vbf8*)(wfb + i * 512);
      #pragma unroll
      for (int t = 0; t < 9; t++) {
        const int ty = t / 3, tx = t % 3;
        const int par = tx & 1;
        const int hx = ocl + (tx >> 1);
        const int f = (hx >> 2) & 1;
        #pragma unroll
        for (int mt = 0; mt < 2; mt++) {
          const int y = 2 * (wv * 2 + mt) + ty;
          const u16* ap = (kg < 2)
              ? &h1[((par * 33 + y) * 17 + hx) * 16 + ((kg ^ f) & 1) * 8]
              : h1;
          vbf8 a = *(const vbf8*)ap;
          #pragma unroll
          for (int nt = 0; nt < 2; nt++)
            accW[mt][nt] = __builtin_amdgcn_mfma_f32_16x16x32_bf16(
                a, bw[t * 2 + nt], accW[mt][nt], 0, 0, 0);
        }
      }
    }
    __syncthreads();
  }

  // ---- WN epilogue: NHWC [z][512][512][32] ----
  #pragma unroll
  for (int mt = 0; mt < 2; mt++) {
    const int oy = oy0 + wv * 2 + mt;
    #pragma unroll
    for (int nt = 0; nt < 2; nt++)
      #pragma unroll
      for (int j = 0; j < 4; j++) {
        const int ox = ox0 + kg * 4 + j;
        h2wb[((size_t)(oy << 9) + ox) * 32 + nt * 16 + ocl] =
            f2b(fmaxf(accW[mt][nt][j], 0.f));
      }
  }

  // ---- BL conv1 ----
  {
    vbf8 wa0 = *(const vbf8*)(g_wfrag + WF_BL1 + lane * 8);
    vbf8 wa1 = *(const vbf8*)(g_wfrag + WF_BL1 + 512 + lane * 8);
    float bias[4];
    #pragma unroll
    for (int j = 0; j < 4; j++) bias[j] = bb1[kg * 4 + j];
    for (int pt = wv; pt < 69; pt += 8) {
      const int p = pt * 16 + ocl;
      const bool ok = (p < 1089);
      const int pc = ok ? p : 1088;
      const int py = pc / 33, px = pc - py * 33;
      const u16* pb = xs4 + (py * 36 + px) * 4;
      vbf8 b0 = ldpair(pb + to0);
      vbf8 b1 = ldpair(pb + to1);
      vf4 acc = {0.f, 0.f, 0.f, 0.f};
      acc = __builtin_amdgcn_mfma_f32_16x16x32_bf16(wa0, b0, acc, 0, 0, 0);
      acc = __builtin_amdgcn_mfma_f32_16x16x32_bf16(wa1, b1, acc, 0, 0, 0);
      if (ok) {
        vs4 pk;
        #pragma unroll
        for (int j = 0; j < 4; j++)
          pk[j] = (short)f2b(fmaxf(acc[j] + bias[j], 0.f));
        const int par = px & 1, hx = px >> 1, f = (hx >> 2) & 1;
        *(vs4*)(&h1[((par * 33 + py) * 17 + hx) * 16 + ((kg >> 1) ^ f) * 8 + (kg & 1) * 4]) = pk;
      }
    }
  }
  __syncthreads();

  // ---- BL conv2 + epilogue ----
  {
    vbf8 bw[9];
    const u16* wfb = g_wfrag + WF_BL2 + lane * 8;
    #pragma unroll
    for (int i = 0; i < 9; i++)
      bw[i] = *(const vbf8*)(wfb + i * 512);
    vf4 accB[2];
    {
      float bv = bb2[ocl];
      vf4 cc; cc[0] = bv; cc[1] = bv; cc[2] = bv; cc[3] = bv;
      accB[0] = cc; accB[1] = cc;
    }
    #pragma unroll
    for (int t = 0; t < 9; t++) {
      const int ty = t / 3, tx = t % 3;
      const int par = tx & 1;
      const int hx = ocl + (tx >> 1);
      const int f = (hx >> 2) & 1;
      #pragma unroll
      for (int mt = 0; mt < 2; mt++) {
        const int y = 2 * (wv * 2 + mt) + ty;
        const u16* ap = (kg < 2)
            ? &h1[((par * 33 + y) * 17 + hx) * 16 + ((kg ^ f) & 1) * 8]
            : h1;
        vbf8 a = *(const vbf8*)ap;
        accB[mt] = __builtin_amdgcn_mfma_f32_16x16x32_bf16(a, bw[t], accB[mt], 0, 0, 0);
      }
    }
    #pragma unroll
    for (int mt = 0; mt < 2; mt++) {
      const int oy = oy0 + wv * 2 + mt;
      #pragma unroll
      for (int j = 0; j < 4; j++) {
        const int ox = ox0 + kg * 4 + j;
        h2bb[((size_t)(oy << 9) + ox) * 16 + ocl] = f2b(fmaxf(accB[mt][j], 0.f));
      }
    }
  }
}

// ---------- stride-2 conv on MFMA (conv3/conv4), NHWC in, 512 threads ----------
template<int CIN, int COUT, int NT, int NG, int KC, bool REDUCE>
__global__ __launch_bounds__(512) void k34m(
    const u16* __restrict__ in, const float* __restrict__ bia,
    int wfo, u16* __restrict__ out, int HIN, int gofs)
{
  constexpr int FS = (NG == 4) ? 1 : 2;
  constexpr int NTF = COUT / 16;
  constexpr int OCG = COUT / (NT * 16);
  __shared__ __align__(16) u16 h1p[2][33][17][NG * 8];
  __shared__ __align__(16) u16 zbuf[8];
  __shared__ float rsum[NT * 16];
  const int HO = HIN >> 1;
  const int tid = threadIdx.x;
  const int lane = tid & 63, wv = tid >> 6;
  const int zb2 = blockIdx.z / OCG;
  const int og = blockIdx.z - zb2 * OCG;
  const int oy0 = blockIdx.y * 16, ox0 = blockIdx.x * 16;
  const int iy0 = 2 * oy0 - 1, ix0 = 2 * ox0 - 1;
  const u16* inb = in + (size_t)zb2 * (size_t)HIN * HIN * CIN;

  if (tid < 8) zbuf[tid] = 0;
  if (REDUCE && tid < NT * 16) rsum[tid] = 0.f;

  const int ocl = lane & 15;
  const int kg  = lane >> 4;

  vf4 acc2[2][NT];
  #pragma unroll
  for (int nt = 0; nt < NT; nt++) {
    float bv = bia[og * NT * 16 + nt * 16 + ocl];
    #pragma unroll
    for (int mt = 0; mt < 2; mt++) {
      vf4 c; c[0] = bv; c[1] = bv; c[2] = bv; c[3] = bv;
      acc2[mt][nt] = c;
    }
  }

  vbf8 bw[9 * NT];

  for (int kc = 0; kc < KC; kc++) {
    if (kc) __syncthreads();
    for (int i = tid; i < 33 * 33 * NG; i += 512) {
      int g = i & (NG - 1);
      int pp = i / NG;
      int yy = pp / 33, xx = pp - yy * 33;
      int gy = iy0 + yy, gx = ix0 + xx;
      vbf8 v = {0, 0, 0, 0, 0, 0, 0, 0};
      if ((unsigned)gy < (unsigned)HIN && (unsigned)gx < (unsigned)HIN)
        v = *(const vbf8*)(inb + (size_t)(gy * HIN + gx) * CIN + kc * 32 + g * 8);
      const int par = xx & 1, hx = xx >> 1;
      const int f = (hx >> FS) & (NG - 1);
      *(vbf8*)(&h1p[par][yy][hx][(g ^ f) * 8]) = v;
    }
    {
      const u16* wfb = g_wfrag + wfo + lane * 8;
      #pragma unroll
      for (int t = 0; t < 9; t++)
        #pragma unroll
        for (int nt = 0; nt < NT; nt++)
          bw[t * NT + nt] =
              *(const vbf8*)(wfb + (size_t)((kc * 9 + t) * NTF + og * NT + nt) * 512);
    }
    __syncthreads();

    #pragma unroll
    for (int t = 0; t < 9; t++) {
      const int ty = t / 3, tx = t % 3;
      const int par = tx & 1;
      const int hx = (lane & 15) + (tx >> 1);
      const int f = (hx >> FS) & (NG - 1);
      #pragma unroll
      for (int mt = 0; mt < 2; mt++) {
        const int y = 2 * (wv * 2 + mt) + ty;
        const u16* ap;
        if constexpr (NG == 4) {
          ap = &h1p[par][y][hx][((kg ^ f) & 3) * 8];
        } else {
          ap = (kg < NG) ? &h1p[par][y][hx][((kg ^ f) & (NG - 1)) * 8] : zbuf;
        }
        vbf8 a = *(const vbf8*)ap;
        #pragma unroll
        for (int nt = 0; nt < NT; nt++)
          acc2[mt][nt] = __builtin_amdgcn_mfma_f32_16x16x32_bf16(
              a, bw[t * NT + nt], acc2[mt][nt], 0, 0, 0);
      }
    }
  }

  if constexpr (REDUCE) {
    #pragma unroll
    for (int nt = 0; nt < NT; nt++) {
      float part = 0.f;
      #pragma unroll
      for (int mt = 0; mt < 2; mt++)
        #pragma unroll
        for (int j = 0; j < 4; j++)
          part += fmaxf(acc2[mt][nt][j], 0.f);
      atomicAdd(&rsum[nt * 16 + ocl], part);
    }
    __syncthreads();
    if (tid < NT * 16)
      atomicAdd(&g_state[gofs + zb2 * COUT + og * NT * 16 + tid],
                rsum[tid] * (1.f / 16384.f));
  } else {
    #pragma unroll
    for (int mt = 0; mt < 2; mt++) {
      const int oy = oy0 + wv * 2 + mt;
      #pragma unroll
      for (int nt = 0; nt < NT; nt++) {
        const int oc = og * NT * 16 + nt * 16 + ocl;
        #pragma unroll
        for (int j = 0; j < 4; j++) {
          const int ox = ox0 + kg * 4 + j;
          out[((size_t)zb2 * HO * HO + (size_t)(oy * HO + ox)) * COUT + oc] =
              f2b(fmaxf(acc2[mt][nt][j], 0.f));
        }
      }
    }
  }
}

// ---------- FC head ----------
template<int CF, int NOUT, bool SIG>
__global__ __launch_bounds__(256) void khead(
    const float* __restrict__ fw1, const float* __restrict__ fb1,
    const float* __restrict__ fw2, const float* __restrict__ fb2,
    int feato, int outo, float* out_f)
{
  __shared__ float fc1[4 * CF];
  const int tid = threadIdx.x;
  if (tid < 4 * CF) {
    int b = tid / CF, o = tid - b * CF;
    float s = fb1[o];
    for (int i = 0; i < CF; i++)
      s = fmaf(g_state[feato + b * CF + i], fw1[o * CF + i], s);
    fc1[tid] = fmaxf(s, 0.f);
  }
  __syncthreads();
  if (tid < 4 * NOUT) {
    int b = tid / NOUT, n = tid - b * NOUT;
    float s = fb2[n];
    for (int i = 0; i < CF; i++)
      s = fmaf(fc1[b * CF + i], fw2[n * CF + i], s);
    if (SIG) s = 1.f / (1.f + expf(-s));
    g_state[outo + b * NOUT + n] = s;
    if (out_f) out_f[b * NOUT + n] = s;
  }
}

// ---------- fused LUT = clip(w3d @ luts + identity, 0,1); also fp16 AoS copy ----------
__global__ __launch_bounds__(256) void kfuse(
    const float* __restrict__ luts, float* __restrict__ outF,
    u16* __restrict__ Fa)
{
  if (blockIdx.x == 0 && threadIdx.x == 0) {
    g_state[GS_ACCS] = 0.f; g_state[GS_ACCS + 1] = 0.f;
  }
  int idx = blockIdx.x * 256 + threadIdx.x;
  if (idx >= 431244) return;
  int n = idx / 107811, m = idx - n * 107811;
  int c = m / 35937, q = m - c * 35937;
  int bq = q / 1089, r2 = q - bq * 1089;
  int gq = r2 / 33, rq = r2 - gq * 33;
  int id = (c == 0) ? rq : (c == 1) ? gq : bq;
  float s = (float)id * (1.f / 32.f);
  #pragma unroll
  for (int k = 0; k < 8; k++)
    s = fmaf(g_state[GS_W3D + n * 8 + k], luts[k * 107811 + m], s);
  s = fminf(fmaxf(s, 0.f), 1.f);
  outF[idx] = s;
  if (Fa) Fa[(n * 35937 + q) * 4 + c] = f2h(s);
}

// ---------- TV + monotonicity reductions over fused ----------
__global__ __launch_bounds__(256) void ktv(const float* __restrict__ f) {
  const int Nr = 418176;
  float tv = 0.f, mn = 0.f;
  for (int e = blockIdx.x * 256 + threadIdx.x; e < 3 * Nr; e += gridDim.x * 256) {
    int dir = e / Nr, j = e - dir * Nr;
    int i, stride; float w;
    if (dir == 0) {
      int r = j & 31; int t = j >> 5;
      int g = t % 33; t /= 33;
      i = t * 1089 + g * 33 + r; stride = 1;
      w = (r == 0 || r == 31) ? 2.f : 1.f;
    } else if (dir == 1) {
      int r = j % 33; int t = j / 33; int g = t & 31; t >>= 5;
      i = t * 1089 + g * 33 + r; stride = 33;
      w = (g == 0 || g == 31) ? 2.f : 1.f;
    } else {
      int r = j % 33; int t = j / 33; int g = t % 33; t /= 33;
      int bb = t & 31; t >>= 5;
      i = (t * 33 + bb) * 1089 + g * 33 + r; stride = 1089;
      w = (bb == 0 || bb == 31) ? 2.f : 1.f;
    }
    float d = f[i] - f[i + stride];
    tv = fmaf(d * d, w, tv);
    mn += fmaxf(d, 0.f);
  }
  __shared__ float r1[256], r2[256];
  r1[threadIdx.x] = tv; r2[threadIdx.x] = mn; __syncthreads();
  for (int st = 128; st > 0; st >>= 1) {
    if (threadIdx.x < st) { r1[threadIdx.x] += r1[threadIdx.x + st];
                            r2[threadIdx.x] += r2[threadIdx.x + st]; }
    __syncthreads();
  }
  if (threadIdx.x == 0) {
    atomicAdd(&g_state[GS_ACCS], r1[0]);
    atomicAdd(&g_state[GS_ACCS + 1], r2[0]);
  }
}

// ---------- trilinear apply, 4 px/thread, fp16 AoS LUT ----------
__global__ __launch_bounds__(256) void kapply4(
    const float* __restrict__ x, const u16* __restrict__ Fa,
    float* __restrict__ out)
{
  int p = blockIdx.x * 256 + threadIdx.x;   // grid 4096
  if (p == 0) {
    out[OUT_TV] = g_state[GS_ACCS] * (1.f / 418176.f);
    out[OUT_MN] = g_state[GS_ACCS + 1] * (1.f / 418176.f);
  }
  const int b = p >> 18;
  const int yx0 = (p & 262143) * 4;
  const size_t base = (size_t)b * 3145728u + yx0;
  vf4 xr = *(const vf4*)(x + base);
  vf4 xg = *(const vf4*)(x + base + 1048576);
  vf4 xb = *(const vf4*)(x + base + 2097152);
  const float a = g_state[GS_BLEND + b];
  const u32* Fu = (const u32*)Fa;

  int cb4[4];
  float fr4[4], fg4[4], fb4[4];
  #pragma unroll
  for (int i = 0; i < 4; i++) {
    float sr = fminf(fmaxf(xr[i], 0.f), 1.f) * 32.f;
    float sg = fminf(fmaxf(xg[i], 0.f), 1.f) * 32.f;
    float sb = fminf(fmaxf(xb[i], 0.f), 1.f) * 32.f;
    int ir = min((int)sr, 31), ig = min((int)sg, 31), ib = min((int)sb, 31);
    fr4[i] = sr - ir; fg4[i] = sg - ig; fb4[i] = sb - ib;
    cb4[i] = b * 35937 + ib * 1089 + ig * 33 + ir;
  }

  u32 q[4][4][4];
  const int off[4] = {0, 33, 1089, 1122};
  #pragma unroll
  for (int i = 0; i < 4; i++)
    #pragma unroll
    for (int pr = 0; pr < 4; pr++) {
      const u32* c0 = Fu + (size_t)(cb4[i] + off[pr]) * 2;
      q[i][pr][0] = c0[0]; q[i][pr][1] = c0[1];
      q[i][pr][2] = c0[2]; q[i][pr][3] = c0[3];
    }

  vf4 o0, o1, o2;
  #pragma unroll
  for (int i = 0; i < 4; i++) {
    const float fr = fr4[i], fg = fg4[i], fb = fb4[i];
    #pragma unroll
    for (int c = 0; c < 3; c++) {
      const int k = c >> 1, sh = (c & 1) * 16;
      float v000 = h2f((u16)(q[i][0][k]     >> sh));
      float v001 = h2f((u16)(q[i][0][2 + k] >> sh));
      float v010 = h2f((u16)(q[i][1][k]     >> sh));
      float v011 = h2f((u16)(q[i][1][2 + k] >> sh));
      float v100 = h2f((u16)(q[i][2][k]     >> sh));
      float v101 = h2f((u16)(q[i][2][2 + k] >> sh));
      float v110 = h2f((u16)(q[i][3][k]     >> sh));
      float v111 = h2f((u16)(q[i][3][2 + k] >> sh));
      float c00 = v000 + fr * (v001 - v000);
      float c01 = v010 + fr * (v011 - v010);
      float c10 = v100 + fr * (v101 - v100);
      float c11 = v110 + fr * (v111 - v110);
      float c0 = c00 + fg * (c01 - c00);
      float c1 = c10 + fg * (c11 - c10);
      float v  = c0 + fb * (c1 - c0);
      float xv = (c == 0) ? xr[i] : (c == 1) ? xg[i] : xb[i];
      float o = fminf(fmaxf((1.f - a) * xv + a * v, 0.f), 1.f);
      if (c == 0) o0[i] = o; else if (c == 1) o1[i] = o; else o2[i] = o;
    }
  }
  *(vf4*)(out + (size_t)(b * 3 + 0) * 1048576u + yx0) = o0;
  *(vf4*)(out + (size_t)(b * 3 + 1) * 1048576u + yx0) = o1;
  *(vf4*)(out + (size_t)(b * 3 + 2) * 1048576u + yx0) = o2;
}

// ---------- trilinear apply, fallback 1 px/thread, fp32 SoA ----------
__global__ __launch_bounds__(256) void kapply1(
    const float* __restrict__ x, const float* __restrict__ F,
    float* __restrict__ out)
{
  int p = blockIdx.x * 256 + threadIdx.x;
  if (p == 0) {
    out[OUT_TV] = g_state[GS_ACCS] * (1.f / 418176.f);
    out[OUT_MN] = g_state[GS_ACCS + 1] * (1.f / 418176.f);
  }
  int b = p >> 20, yx = p & 1048575;
  size_t base = (size_t)b * 3145728u + yx;
  float xr = x[base];
  float xg = x[base + 1048576];
  float xb = x[base + 2097152];
  float a = g_state[GS_BLEND + b];
  float sr = fminf(fmaxf(xr, 0.f), 1.f) * 32.f;
  float sg = fminf(fmaxf(xg, 0.f), 1.f) * 32.f;
  float sb = fminf(fmaxf(xb, 0.f), 1.f) * 32.f;
  int ir = min((int)sr, 31), ig = min((int)sg, 31), ib = min((int)sb, 31);
  float fr = sr - ir, fg = sg - ig, fb = sb - ib;
  const float* Fb = F + (size_t)b * 107811u + ib * 1089 + ig * 33 + ir;
  #pragma unroll
  for (int c = 0; c < 3; c++) {
    const float* Fc = Fb + c * 35937;
    float v000 = Fc[0],    v001 = Fc[1];
    float v010 = Fc[33],   v011 = Fc[34];
    float v100 = Fc[1089], v101 = Fc[1090];
    float v110 = Fc[1122], v111 = Fc[1123];
    float c00 = v000 + fr * (v001 - v000);
    float c01 = v010 + fr * (v011 - v010);
    float c10 = v100 + fr * (v101 - v100);
    float c11 = v110 + fr * (v111 - v110);
    float c0 = c00 + fg * (c01 - c00);
    float c1 = c10 + fg * (c11 - c10);
    float v  = c0 + fb * (c1 - c0);
    float xv = (c == 0) ? xr : (c == 1) ? xg : xb;
    float o = fminf(fmaxf((1.f - a) * xv + a * v, 0.f), 1.f);
    out[(size_t)(b * 3 + c) * 1048576u + yx] = o;
  }
}

extern "C" void kernel_launch(void* const* d_in, const int* in_sizes, int n_in,
                              void* d_out, int out_size, void* d_ws, size_t ws_size,
                              hipStream_t stream)
{
  (void)in_sizes; (void)n_in; (void)out_size;
  const float* x    = (const float*)d_in[0];
  const float* luts = (const float*)d_in[1];
  const float* wn_b1 = (const float*)d_in[3];
  const float* wn_b2 = (const float*)d_in[5];
  const float* wn_b3 = (const float*)d_in[7];
  const float* wn_b4 = (const float*)d_in[9];
  const float* wn_fw1 = (const float*)d_in[10], *wn_fb1 = (const float*)d_in[11];
  const float* wn_fw2 = (const float*)d_in[12], *wn_fb2 = (const float*)d_in[13];
  const float* bl_b1 = (const float*)d_in[15];
  const float* bl_b2 = (const float*)d_in[17];
  const float* bl_b3 = (const float*)d_in[19];
  const float* bl_b4 = (const float*)d_in[21];
  const float* bl_fw1 = (const float*)d_in[22], *bl_fb1 = (const float*)d_in[23];
  const float* bl_fw2 = (const float*)d_in[24], *bl_fb2 = (const float*)d_in[25];
  float* out = (float*)d_out;
  const bool hasWs = (ws_size >= 50331648u);

  P2Args p2;
  const float* wsrc[8] = {(const float*)d_in[4],  (const float*)d_in[16],
                          (const float*)d_in[6],  (const float*)d_in[8],
                          (const float*)d_in[18], (const float*)d_in[20],
                          (const float*)d_in[2],  (const float*)d_in[14]};
  const int pI[8]   = {32, 16, 32, 64, 16, 32, 3, 3};
  const int pNTF[8] = {2, 1, 4, 4, 2, 2, 2, 1};
  const int pB[8]   = {WF_WN2, WF_BL2, WF_WN3, WF_WN4, WF_BL3, WF_BL4,
                       WF_WN1, WF_BL1};
  const int pHK[8]  = {1, 0, 0, 0, 0, 0, 0, 0};
  for (int l = 0; l < 8; l++) { p2.w[l] = wsrc[l]; p2.I[l] = pI[l];
                                p2.ntf[l] = pNTF[l]; p2.base[l] = pB[l];
                                p2.halfk[l] = pHK[l]; }
  kprep2<<<dim3(390), 256, 0, stream>>>(p2);

  if (hasWs) {
    u16* scrA = (u16*)d_ws;                    // WN h2: 33.6 MB
    u16* scrB = (u16*)d_ws + 16777216;         // conv3 out: up to 16.8 MB
    u16* blh2 = (u16*)out;                     // BL h2: 16.8 MB (out scratch)
    u16* Fa   = (u16*)d_ws;                    // fp16 AoS LUT (post-conv)

    for (int b0 = 0; b0 < 4; b0 += 2) {
      const float* xb = x + (size_t)b0 * 3145728u;
      k12d<<<dim3(32,32,2), 512, 0, stream>>>(xb, wn_b1, wn_b2, bl_b1, bl_b2,
                                              scrA, blh2);
      k34m<32,64,2,4,1,false><<<dim3(16,16,4), 512, 0, stream>>>(scrA, wn_b3, WF_WN3, scrB, 512, 0);
      k34m<64,64,2,4,2,true ><<<dim3(8,8,4),   512, 0, stream>>>(scrB, wn_b4, WF_WN4, nullptr, 256, GS_FEATWN + b0 * 64);
      k34m<16,32,2,2,1,false><<<dim3(16,16,2), 512, 0, stream>>>(blh2, bl_b3, WF_BL3, scrB, 512, 0);
      k34m<32,32,2,4,1,true ><<<dim3(8,8,2),   512, 0, stream>>>(scrB, bl_b4, WF_BL4, nullptr, 256, GS_FEATBL + b0 * 32);
    }
    khead<64,8,false><<<1,256,0,stream>>>(wn_fw1, wn_fb1, wn_fw2, wn_fb2,
                                          GS_FEATWN, GS_W3D, out + OUT_W3D);
    khead<32,1,true ><<<1,256,0,stream>>>(bl_fw1, bl_fb1, bl_fw2, bl_fb2,
                                          GS_FEATBL, GS_BLEND, (float*)nullptr);

    kfuse<<<1685, 256, 0, stream>>>(luts, out + OUT_FUSED, Fa);
    ktv<<<512, 256, 0, stream>>>(out + OUT_FUSED);
    kapply4<<<4096, 256, 0, stream>>>(x, Fa, out);
  } else {
    // 1-batch passes so all scratch fits inside d_out (33.6 MB peak)
    u16* h2wF  = (u16*)out;                 // 16.8 MB
    u16* h2bF  = (u16*)out + 8388608;       // 8.4 MB
    u16* scrBF = (u16*)out + 12582912;      // 8.4 MB

    for (int b = 0; b < 4; b++) {
      const float* xb = x + (size_t)b * 3145728u;
      k12d<<<dim3(32,32,1), 512, 0, stream>>>(xb, wn_b1, wn_b2, bl_b1, bl_b2,
                                              h2wF, h2bF);
      k34m<32,64,2,4,1,false><<<dim3(16,16,2), 512, 0, stream>>>(h2wF, wn_b3, WF_WN3, scrBF, 512, 0);
      k34m<64,64,2,4,2,true ><<<dim3(8,8,2),   512, 0, stream>>>(scrBF, wn_b4, WF_WN4, nullptr, 256, GS_FEATWN + b * 64);
      k34m<16,32,2,2,1,false><<<dim3(16,16,1), 512, 0, stream>>>(h2bF, bl_b3, WF_BL3, scrBF, 512, 0);
      k34m<32,32,2,4,1,true ><<<dim3(8,8,1),   512, 0, stream>>>(scrBF, bl_b4, WF_BL4, nullptr, 256, GS_FEATBL + b * 32);
    }
    khead<64,8,false><<<1,256,0,stream>>>(wn_fw1, wn_fb1, wn_fw2, wn_fb2,
                                          GS_FEATWN, GS_W3D, out + OUT_W3D);
    khead<32,1,true ><<<1,256,0,stream>>>(bl_fw1, bl_fb1, bl_fw2, bl_fb2,
                                          GS_FEATBL, GS_BLEND, (float*)nullptr);

    kfuse<<<1685, 256, 0, stream>>>(luts, out + OUT_FUSED, nullptr);
    ktv<<<512, 256, 0, stream>>>(out + OUT_FUSED);
    kapply1<<<16384, 256, 0, stream>>>(x, out + OUT_FUSED, out);
  }
}

// Round 9
// 431.269 us; speedup vs baseline: 1.1708x; 1.1144x over previous
//
#include <hip/hip_runtime.h>

typedef unsigned short u16;
typedef unsigned int u32;
typedef __attribute__((ext_vector_type(8))) short vbf8;   // 8 bf16 = 4 VGPR
typedef __attribute__((ext_vector_type(4))) short vs4;    // 4 bf16 = 8 B
typedef __attribute__((ext_vector_type(4))) float vf4;    // MFMA acc / float4

// ---------- bf16 <-> f32 (bitwise; RNE on pack) ----------
__device__ __forceinline__ float b2f(u16 u) {
  union { unsigned int i; float f; } v; v.i = ((unsigned int)u) << 16; return v.f;
}
__device__ __forceinline__ u16 f2b(float f) {
  union { float f; unsigned int i; } v; v.f = f;
  unsigned int r = v.i + 0x7fffu + ((v.i >> 16) & 1u);
  return (u16)(r >> 16);
}
__device__ __forceinline__ u16 f2h(float f) {
  union { _Float16 h; u16 s; } cv; cv.h = (_Float16)f; return cv.s;
}
__device__ __forceinline__ float h2f(u16 u) {
  union { _Float16 h; u16 s; } cv; cv.s = u; return (float)cv.h;
}
// two 8B LDS reads -> one bf16x8 fragment (8B-aligned safe)
__device__ __forceinline__ vbf8 ldpair(const u16* p) {
  vs4 lo = *(const vs4*)p;
  vs4 hi = *(const vs4*)(p + 4);
  return __builtin_shufflevector(lo, hi, 0, 1, 2, 3, 4, 5, 6, 7);
}

// ---------- tiny cross-kernel state ------
__device__ float g_state[512];
#define GS_FEATWN 0      // 256
#define GS_FEATBL 256    // 128
#define GS_W3D    384    // 32
#define GS_BLEND  416    // 4
#define GS_ACCS   420    // 2

// ---------- MFMA-fragment-ordered bf16 conv weights ----------
// conv2..4 (full-K): elem (l,j) = W[oc=nt*16+(l&15)][ic=kc*32+(l>>4)*8+j][t];
//   frag idx = (kc*9+t)*NTF + nt ; ic >= I zero-pad.
// conv1 tap-pair: k = kg*8 + tp*4 + ic; pair starts {0,3,6,2} (g0), {5,8,-,-} (g1);
//   tp=1 taps {1,4,7} (g0 only); ic>=3 or dead -> 0. WN: 2 oc-chunks x 2 groups.
__device__ __align__(16) u16 g_wfrag[90624];
#define WF_WN2 0       // 18 frags (full-K)
#define WF_BL2 9216    //  9
#define WF_WN3 13824   // 36
#define WF_WN4 32256   // 72
#define WF_BL3 69120   // 18 (I=16 zero-pad)
#define WF_BL4 78336   // 18
#define WF_WN1 87552   //  4 (2 oc-chunks x 2 groups)
#define WF_BL1 89600   //  2

// ---------- output layout (fp32 elements) ----------
#define OUT_FUSED 12582912
#define OUT_TV    13014156
#define OUT_MN    13014157
#define OUT_W3D   13014158

// ---------- prep: pack all conv weights into MFMA fragment order ----------
struct P2Args { const float* w[8]; int I[8]; int ntf[8]; int base[8]; };

__global__ __launch_bounds__(256) void kprep2(P2Args a) {
  if (blockIdx.x == 0 && threadIdx.x < 256) {
    g_state[threadIdx.x] = 0.f;
    if (threadIdx.x < 128) g_state[256 + threadIdx.x] = 0.f;
  }
  int i = blockIdx.x * 256 + threadIdx.x;   // grid 354*256 = 90624 exact
  int l = 0;
  #pragma unroll
  for (int k = 1; k < 8; k++) if (i >= a.base[k]) l = k;
  int e2 = i - a.base[l];
  int frag = e2 >> 9, e = e2 & 511;
  int ll = e >> 3, j = e & 7;
  if (l < 6) {
    int NTF = a.ntf[l];
    int kc = frag / (9 * NTF);
    int r = frag - kc * 9 * NTF;
    int t = r / NTF, nt = r - t * NTF;
    int I = a.I[l];
    int oc = nt * 16 + (ll & 15);
    int ic = kc * 32 + (ll >> 4) * 8 + j;
    g_wfrag[i] = (ic < I) ? f2b(a.w[l][(oc * I + ic) * 9 + t]) : (u16)0;
  } else {
    // conv1 tap-pair packing
    int isWN = (l == 6);
    int c2 = isWN ? (frag >> 1) : 0;
    int g = isWN ? (frag & 1) : frag;
    int idx = g * 4 + (ll >> 4);
    int tp = j >> 2, ic = j & 3;
    int tap = (tp == 0)
        ? ((idx == 0) ? 0 : (idx == 1) ? 3 : (idx == 2) ? 6 :
           (idx == 3) ? 2 : (idx == 4) ? 5 : (idx == 5) ? 8 : -1)
        : ((idx == 0) ? 1 : (idx == 1) ? 4 : (idx == 2) ? 7 : -1);
    int oc = c2 * 16 + (ll & 15);
    g_wfrag[i] = (ic < 3 && tap >= 0) ? f2b(a.w[l][oc * 27 + ic * 9 + tap]) : (u16)0;
  }
}

// ---------- merged WN+BL conv1+conv2, 512 thr, 81.6 KB LDS, 2 blk/CU ----------
// xs4 [35][35][4]; h1 32-ch NG=4 for WN (full-K conv2), first half reused by BL.
__global__ __launch_bounds__(512, 4) void k12d(
    const float* __restrict__ x,
    const float* __restrict__ wb1, const float* __restrict__ wb2,
    const float* __restrict__ bb1, const float* __restrict__ bb2,
    u16* __restrict__ h2w, u16* __restrict__ h2b)
{
  __shared__ __align__(16) u16 xs4[4908];    // 35*35*4 + 8 guard = 9,816 B
  __shared__ __align__(16) u16 h1w[35904];   // [2][33][17][32] = 71,808 B
  const int tid = threadIdx.x;
  const int lane = tid & 63, wv = tid >> 6;
  const int ocl = lane & 15;
  const int kg  = lane >> 4;
  const int oy0 = blockIdx.y * 16, ox0 = blockIdx.x * 16;
  const int hy0 = 2 * oy0 - 1, hx0 = 2 * ox0 - 1;
  const float* xb = x + (size_t)blockIdx.z * 3145728u;
  u16* h2wb = h2w + (size_t)blockIdx.z * 8388608u;
  u16* h2bb = h2b + (size_t)blockIdx.z * 4194304u;

  // ---- stage x as 4-ch NHWC bf16 ----
  for (int i = tid; i < 1225; i += 512) {
    int yy = i / 35, xx = i - yy * 35;
    int gy = hy0 - 1 + yy, gx = hx0 - 1 + xx;
    vs4 v = {0, 0, 0, 0};
    if ((unsigned)gy < 1024u && (unsigned)gx < 1024u) {
      const float* pp = xb + (gy << 10) + gx;
      v[0] = (short)f2b(pp[0]);
      v[1] = (short)f2b(pp[1048576]);
      v[2] = (short)f2b(pp[2097152]);
    }
    *(vs4*)(&xs4[(yy * 35 + xx) * 4]) = v;
  }

  // tap-pair B-frag u16 offsets (35-wide rows)
  const int to0 = (kg < 3) ? kg * 140 : 8;        // pair starts taps {0,3,6,2}
  const int to1 = (kg == 0) ? 148 : 288;          // {5,8,dead,dead}

  // WN conv1 weight frags + biases
  vbf8 waW[4];
  float bias1[2][4];
  {
    const u16* wfb = g_wfrag + WF_WN1 + lane * 8;
    #pragma unroll
    for (int q = 0; q < 4; q++) waW[q] = *(const vbf8*)(wfb + q * 512);
    #pragma unroll
    for (int j = 0; j < 4; j++) {
      bias1[0][j] = wb1[kg * 4 + j];
      bias1[1][j] = wb1[16 + kg * 4 + j];
    }
  }
  __syncthreads();

  // ---- conv1 WN: both oc-chunks, shared B-frags ----
  for (int pt = wv; pt < 69; pt += 8) {
    const int p = pt * 16 + ocl;
    const bool ok = (p < 1089);
    const int pc = ok ? p : 1088;
    const int py = pc / 33, px = pc - py * 33;
    const u16* pb = xs4 + (py * 35 + px) * 4;
    vbf8 b0 = ldpair(pb + to0);
    vbf8 b1 = ldpair(pb + to1);
    const int par = px & 1, hx = px >> 1;
    const int f = (hx >> 1) & 3;
    const int hb = ((par * 33 + py) * 17 + hx) * 32;
    #pragma unroll
    for (int c = 0; c < 2; c++) {
      vf4 acc = {0.f, 0.f, 0.f, 0.f};
      acc = __builtin_amdgcn_mfma_f32_16x16x32_bf16(waW[c * 2 + 0], b0, acc, 0, 0, 0);
      acc = __builtin_amdgcn_mfma_f32_16x16x32_bf16(waW[c * 2 + 1], b1, acc, 0, 0, 0);
      if (ok) {
        vs4 pk;
        #pragma unroll
        for (int j = 0; j < 4; j++)
          pk[j] = (short)f2b(fmaxf(acc[j] + bias1[c][j], 0.f));
        const int q = (c << 2) + kg;
        *(vs4*)(&h1w[hb + ((q >> 1) ^ f) * 8 + (q & 1) * 4]) = pk;
      }
    }
  }
  __syncthreads();

  // ---- conv2 WN: full-K (NT=2, NG=4) ----
  {
    vbf8 bw[18];
    const u16* wfb = g_wfrag + WF_WN2 + lane * 8;
    #pragma unroll
    for (int i = 0; i < 18; i++)
      bw[i] = *(const vbf8*)(wfb + i * 512);

    vf4 acc2[2][2];
    #pragma unroll
    for (int nt = 0; nt < 2; nt++) {
      float bv = wb2[nt * 16 + ocl];
      vf4 cc; cc[0] = bv; cc[1] = bv; cc[2] = bv; cc[3] = bv;
      acc2[0][nt] = cc; acc2[1][nt] = cc;
    }
    #pragma unroll
    for (int t = 0; t < 9; t++) {
      const int ty = t / 3, tx = t % 3;
      const int par = tx & 1;
      const int hx = ocl + (tx >> 1);
      const int f = (hx >> 1) & 3;
      #pragma unroll
      for (int mt = 0; mt < 2; mt++) {
        const int y = 2 * (wv * 2 + mt) + ty;
        vbf8 a = *(const vbf8*)(&h1w[((par * 33 + y) * 17 + hx) * 32 + ((kg ^ f) & 3) * 8]);
        #pragma unroll
        for (int nt = 0; nt < 2; nt++)
          acc2[mt][nt] = __builtin_amdgcn_mfma_f32_16x16x32_bf16(
              a, bw[t * 2 + nt], acc2[mt][nt], 0, 0, 0);
      }
    }
    #pragma unroll
    for (int mt = 0; mt < 2; mt++) {
      const int oy = oy0 + wv * 2 + mt;
      #pragma unroll
      for (int nt = 0; nt < 2; nt++)
        #pragma unroll
        for (int j = 0; j < 4; j++) {
          const int ox = ox0 + kg * 4 + j;
          h2wb[((size_t)(oy << 9) + ox) * 32 + nt * 16 + ocl] =
              f2b(fmaxf(acc2[mt][nt][j], 0.f));
        }
    }
  }
  __syncthreads();

  // ---- conv1 BL (writes first half of h1w as [2][33][17][16]) ----
  {
    vbf8 wa0 = *(const vbf8*)(g_wfrag + WF_BL1 + lane * 8);
    vbf8 wa1 = *(const vbf8*)(g_wfrag + WF_BL1 + 512 + lane * 8);
    float bias[4];
    #pragma unroll
    for (int j = 0; j < 4; j++) bias[j] = bb1[kg * 4 + j];
    for (int pt = wv; pt < 69; pt += 8) {
      const int p = pt * 16 + ocl;
      const bool ok = (p < 1089);
      const int pc = ok ? p : 1088;
      const int py = pc / 33, px = pc - py * 33;
      const u16* pb = xs4 + (py * 35 + px) * 4;
      vbf8 b0 = ldpair(pb + to0);
      vbf8 b1 = ldpair(pb + to1);
      vf4 acc = {0.f, 0.f, 0.f, 0.f};
      acc = __builtin_amdgcn_mfma_f32_16x16x32_bf16(wa0, b0, acc, 0, 0, 0);
      acc = __builtin_amdgcn_mfma_f32_16x16x32_bf16(wa1, b1, acc, 0, 0, 0);
      if (ok) {
        vs4 pk;
        #pragma unroll
        for (int j = 0; j < 4; j++)
          pk[j] = (short)f2b(fmaxf(acc[j] + bias[j], 0.f));
        const int par = px & 1, hx = px >> 1, f = (hx >> 2) & 1;
        *(vs4*)(&h1w[((par * 33 + py) * 17 + hx) * 16 + ((kg >> 1) ^ f) * 8 + (kg & 1) * 4]) = pk;
      }
    }
  }
  __syncthreads();

  // ---- conv2 BL (NT=1, NG=2) ----
  {
    vbf8 bw[9];
    const u16* wfb = g_wfrag + WF_BL2 + lane * 8;
    #pragma unroll
    for (int i = 0; i < 9; i++)
      bw[i] = *(const vbf8*)(wfb + i * 512);
    vf4 accB[2];
    {
      float bv = bb2[ocl];
      vf4 cc; cc[0] = bv; cc[1] = bv; cc[2] = bv; cc[3] = bv;
      accB[0] = cc; accB[1] = cc;
    }
    #pragma unroll
    for (int t = 0; t < 9; t++) {
      const int ty = t / 3, tx = t % 3;
      const int par = tx & 1;
      const int hx = ocl + (tx >> 1);
      const int f = (hx >> 2) & 1;
      #pragma unroll
      for (int mt = 0; mt < 2; mt++) {
        const int y = 2 * (wv * 2 + mt) + ty;
        const u16* ap = (kg < 2)
            ? &h1w[((par * 33 + y) * 17 + hx) * 16 + ((kg ^ f) & 1) * 8]
            : h1w;   // dead lanes: weights are zero
        vbf8 a = *(const vbf8*)ap;
        accB[mt] = __builtin_amdgcn_mfma_f32_16x16x32_bf16(a, bw[t], accB[mt], 0, 0, 0);
      }
    }
    #pragma unroll
    for (int mt = 0; mt < 2; mt++) {
      const int oy = oy0 + wv * 2 + mt;
      #pragma unroll
      for (int j = 0; j < 4; j++) {
        const int ox = ox0 + kg * 4 + j;
        h2bb[((size_t)(oy << 9) + ox) * 16 + ocl] = f2b(fmaxf(accB[mt][j], 0.f));
      }
    }
  }
}

// ---------- stride-2 conv body (conv3/conv4), NHWC in, 512 threads ----------
template<int CIN, int COUT, int NT, int NG, int KC, bool REDUCE>
__device__ __forceinline__ void k34body(
    const u16* __restrict__ in, const float* __restrict__ bia,
    int wfo, u16* __restrict__ out, int HIN, int gofs, int zb2, int og,
    u16* h1p, u16* zbuf, float* rsum)
{
  constexpr int FS = (NG == 4) ? 1 : 2;
  constexpr int NTF = COUT / 16;
  constexpr int RS = NG * 8;
  const int HO = HIN >> 1;
  const int tid = threadIdx.x;
  const int lane = tid & 63, wv = tid >> 6;
  const int oy0 = blockIdx.y * 16, ox0 = blockIdx.x * 16;
  const int iy0 = 2 * oy0 - 1, ix0 = 2 * ox0 - 1;
  const u16* inb = in + (size_t)zb2 * (size_t)HIN * HIN * CIN;

  if (tid < 8) zbuf[tid] = 0;
  if (REDUCE && tid < NT * 16) rsum[tid] = 0.f;

  const int ocl = lane & 15;
  const int kg  = lane >> 4;

  vf4 acc2[2][NT];
  #pragma unroll
  for (int nt = 0; nt < NT; nt++) {
    float bv = bia[og * NT * 16 + nt * 16 + ocl];
    #pragma unroll
    for (int mt = 0; mt < 2; mt++) {
      vf4 c; c[0] = bv; c[1] = bv; c[2] = bv; c[3] = bv;
      acc2[mt][nt] = c;
    }
  }

  vbf8 bw[9 * NT];

  for (int kc = 0; kc < KC; kc++) {
    if (kc) __syncthreads();
    for (int i = tid; i < 33 * 33 * NG; i += 512) {
      int g = i & (NG - 1);
      int pp = i / NG;
      int yy = pp / 33, xx = pp - yy * 33;
      int gy = iy0 + yy, gx = ix0 + xx;
      vbf8 v = {0, 0, 0, 0, 0, 0, 0, 0};
      if ((unsigned)gy < (unsigned)HIN && (unsigned)gx < (unsigned)HIN)
        v = *(const vbf8*)(inb + (size_t)(gy * HIN + gx) * CIN + kc * 32 + g * 8);
      const int par = xx & 1, hx = xx >> 1;
      const int f = (hx >> FS) & (NG - 1);
      *(vbf8*)(&h1p[((par * 33 + yy) * 17 + hx) * RS + (g ^ f) * 8]) = v;
    }
    {
      const u16* wfb = g_wfrag + wfo + lane * 8;
      #pragma unroll
      for (int t = 0; t < 9; t++)
        #pragma unroll
        for (int nt = 0; nt < NT; nt++)
          bw[t * NT + nt] =
              *(const vbf8*)(wfb + (size_t)((kc * 9 + t) * NTF + og * NT + nt) * 512);
    }
    __syncthreads();

    #pragma unroll
    for (int t = 0; t < 9; t++) {
      const int ty = t / 3, tx = t % 3;
      const int par = tx & 1;
      const int hx = (lane & 15) + (tx >> 1);
      const int f = (hx >> FS) & (NG - 1);
      #pragma unroll
      for (int mt = 0; mt < 2; mt++) {
        const int y = 2 * (wv * 2 + mt) + ty;
        const u16* ap;
        if constexpr (NG == 4) {
          ap = &h1p[((par * 33 + y) * 17 + hx) * RS + ((kg ^ f) & 3) * 8];
        } else {
          ap = (kg < NG) ? &h1p[((par * 33 + y) * 17 + hx) * RS + ((kg ^ f) & (NG - 1)) * 8]
                         : zbuf;
        }
        vbf8 a = *(const vbf8*)ap;
        #pragma unroll
        for (int nt = 0; nt < NT; nt++)
          acc2[mt][nt] = __builtin_amdgcn_mfma_f32_16x16x32_bf16(
              a, bw[t * NT + nt], acc2[mt][nt], 0, 0, 0);
      }
    }
  }

  if constexpr (REDUCE) {
    #pragma unroll
    for (int nt = 0; nt < NT; nt++) {
      float part = 0.f;
      #pragma unroll
      for (int mt = 0; mt < 2; mt++)
        #pragma unroll
        for (int j = 0; j < 4; j++)
          part += fmaxf(acc2[mt][nt][j], 0.f);
      atomicAdd(&rsum[nt * 16 + ocl], part);
    }
    __syncthreads();
    if (tid < NT * 16)
      atomicAdd(&g_state[gofs + zb2 * COUT + og * NT * 16 + tid],
                rsum[tid] * (1.f / 16384.f));
  } else {
    #pragma unroll
    for (int mt = 0; mt < 2; mt++) {
      const int oy = oy0 + wv * 2 + mt;
      #pragma unroll
      for (int nt = 0; nt < NT; nt++) {
        const int oc = og * NT * 16 + nt * 16 + ocl;
        #pragma unroll
        for (int j = 0; j < 4; j++) {
          const int ox = ox0 + kg * 4 + j;
          out[((size_t)zb2 * HO * HO + (size_t)(oy * HO + ox)) * COUT + oc] =
              f2b(fmaxf(acc2[mt][nt][j], 0.f));
        }
      }
    }
  }
}

// ---------- merged conv3 (WN z<zwn, BL else) ----------
__global__ __launch_bounds__(512, 2) void kc3(
    const u16* __restrict__ inW, const float* __restrict__ bW, u16* __restrict__ outW,
    const u16* __restrict__ inB, const float* __restrict__ bB, u16* __restrict__ outB,
    int zwn)
{
  __shared__ __align__(16) u16 h1sh[35904];
  __shared__ __align__(16) u16 zbuf[8];
  __shared__ float rsum[32];
  const int z = blockIdx.z;
  if (z < zwn)
    k34body<32, 64, 2, 4, 1, false>(inW, bW, WF_WN3, outW, 512, 0, z >> 1, z & 1,
                                    h1sh, zbuf, rsum);
  else
    k34body<16, 32, 2, 2, 1, false>(inB, bB, WF_BL3, outB, 512, 0, z - zwn, 0,
                                    h1sh, zbuf, rsum);
}

// ---------- merged conv4 (WN z<zwn, BL else), fused mean-reduce ----------
__global__ __launch_bounds__(512, 2) void kc4(
    const u16* __restrict__ inW, const float* __restrict__ bW, int gofsW,
    const u16* __restrict__ inB, const float* __restrict__ bB, int gofsB,
    int zwn)
{
  __shared__ __align__(16) u16 h1sh[35904];
  __shared__ __align__(16) u16 zbuf[8];
  __shared__ float rsum[32];
  const int z = blockIdx.z;
  if (z < zwn)
    k34body<64, 64, 2, 4, 2, true>(inW, bW, WF_WN4, nullptr, 256, gofsW, z >> 1, z & 1,
                                   h1sh, zbuf, rsum);
  else
    k34body<32, 32, 2, 4, 1, true>(inB, bB, WF_BL4, nullptr, 256, gofsB, z - zwn, 0,
                                   h1sh, zbuf, rsum);
}

// ---------- FC heads (merged) ----------
template<int CF, int NOUT, bool SIG>
__device__ __forceinline__ void khead_body(
    const float* __restrict__ fw1, const float* __restrict__ fb1,
    const float* __restrict__ fw2, const float* __restrict__ fb2,
    int feato, int outo, float* out_f, float* fc1)
{
  const int tid = threadIdx.x;
  if (tid < 4 * CF) {
    int b = tid / CF, o = tid - b * CF;
    float s = fb1[o];
    for (int i = 0; i < CF; i++)
      s = fmaf(g_state[feato + b * CF + i], fw1[o * CF + i], s);
    fc1[tid] = fmaxf(s, 0.f);
  }
  __syncthreads();
  if (tid < 4 * NOUT) {
    int b = tid / NOUT, n = tid - b * NOUT;
    float s = fb2[n];
    for (int i = 0; i < CF; i++)
      s = fmaf(fc1[b * CF + i], fw2[n * CF + i], s);
    if (SIG) s = 1.f / (1.f + expf(-s));
    g_state[outo + b * NOUT + n] = s;
    if (out_f) out_f[b * NOUT + n] = s;
  }
}

__global__ __launch_bounds__(256) void kheads(
    const float* __restrict__ wfw1, const float* __restrict__ wfb1,
    const float* __restrict__ wfw2, const float* __restrict__ wfb2,
    const float* __restrict__ bfw1, const float* __restrict__ bfb1,
    const float* __restrict__ bfw2, const float* __restrict__ bfb2,
    float* out_w3d)
{
  __shared__ float fc1[256];
  if (blockIdx.x == 0)
    khead_body<64, 8, false>(wfw1, wfb1, wfw2, wfb2, GS_FEATWN, GS_W3D, out_w3d, fc1);
  else
    khead_body<32, 1, true>(bfw1, bfb1, bfw2, bfb2, GS_FEATBL, GS_BLEND, nullptr, fc1);
}

// ---------- fused LUT = clip(w3d @ luts + identity, 0,1); also fp16 AoS copy ----------
__global__ __launch_bounds__(256) void kfuse(
    const float* __restrict__ luts, float* __restrict__ outF,
    u16* __restrict__ Fa)
{
  if (blockIdx.x == 0 && threadIdx.x == 0) {
    g_state[GS_ACCS] = 0.f; g_state[GS_ACCS + 1] = 0.f;
  }
  int idx = blockIdx.x * 256 + threadIdx.x;
  if (idx >= 431244) return;
  int n = idx / 107811, m = idx - n * 107811;
  int c = m / 35937, q = m - c * 35937;
  int bq = q / 1089, r2 = q - bq * 1089;
  int gq = r2 / 33, rq = r2 - gq * 33;
  int id = (c == 0) ? rq : (c == 1) ? gq : bq;
  float s = (float)id * (1.f / 32.f);
  #pragma unroll
  for (int k = 0; k < 8; k++)
    s = fmaf(g_state[GS_W3D + n * 8 + k], luts[k * 107811 + m], s);
  s = fminf(fmaxf(s, 0.f), 1.f);
  outF[idx] = s;
  if (Fa) Fa[(n * 35937 + q) * 4 + c] = f2h(s);
}

// ---------- TV + monotonicity reductions over fused ----------
__global__ __launch_bounds__(256) void ktv(const float* __restrict__ f) {
  const int Nr = 418176;
  float tv = 0.f, mn = 0.f;
  for (int e = blockIdx.x * 256 + threadIdx.x; e < 3 * Nr; e += gridDim.x * 256) {
    int dir = e / Nr, j = e - dir * Nr;
    int i, stride; float w;
    if (dir == 0) {
      int r = j & 31; int t = j >> 5;
      int g = t % 33; t /= 33;
      i = t * 1089 + g * 33 + r; stride = 1;
      w = (r == 0 || r == 31) ? 2.f : 1.f;
    } else if (dir == 1) {
      int r = j % 33; int t = j / 33; int g = t & 31; t >>= 5;
      i = t * 1089 + g * 33 + r; stride = 33;
      w = (g == 0 || g == 31) ? 2.f : 1.f;
    } else {
      int r = j % 33; int t = j / 33; int g = t % 33; t /= 33;
      int bb = t & 31; t >>= 5;
      i = (t * 33 + bb) * 1089 + g * 33 + r; stride = 1089;
      w = (bb == 0 || bb == 31) ? 2.f : 1.f;
    }
    float d = f[i] - f[i + stride];
    tv = fmaf(d * d, w, tv);
    mn += fmaxf(d, 0.f);
  }
  __shared__ float r1[256], r2[256];
  r1[threadIdx.x] = tv; r2[threadIdx.x] = mn; __syncthreads();
  for (int st = 128; st > 0; st >>= 1) {
    if (threadIdx.x < st) { r1[threadIdx.x] += r1[threadIdx.x + st];
                            r2[threadIdx.x] += r2[threadIdx.x + st]; }
    __syncthreads();
  }
  if (threadIdx.x == 0) {
    atomicAdd(&g_state[GS_ACCS], r1[0]);
    atomicAdd(&g_state[GS_ACCS + 1], r2[0]);
  }
}

// ---------- trilinear apply, 4 px/thread, fp16 AoS LUT ----------
__global__ __launch_bounds__(256) void kapply4(
    const float* __restrict__ x, const u16* __restrict__ Fa,
    float* __restrict__ out)
{
  int p = blockIdx.x * 256 + threadIdx.x;   // grid 4096
  if (p == 0) {
    out[OUT_TV] = g_state[GS_ACCS] * (1.f / 418176.f);
    out[OUT_MN] = g_state[GS_ACCS + 1] * (1.f / 418176.f);
  }
  const int b = p >> 18;
  const int yx0 = (p & 262143) * 4;
  const size_t base = (size_t)b * 3145728u + yx0;
  vf4 xr = *(const vf4*)(x + base);
  vf4 xg = *(const vf4*)(x + base + 1048576);
  vf4 xb = *(const vf4*)(x + base + 2097152);
  const float a = g_state[GS_BLEND + b];
  const u32* Fu = (const u32*)Fa;

  int cb4[4];
  float fr4[4], fg4[4], fb4[4];
  #pragma unroll
  for (int i = 0; i < 4; i++) {
    float sr = fminf(fmaxf(xr[i], 0.f), 1.f) * 32.f;
    float sg = fminf(fmaxf(xg[i], 0.f), 1.f) * 32.f;
    float sb = fminf(fmaxf(xb[i], 0.f), 1.f) * 32.f;
    int ir = min((int)sr, 31), ig = min((int)sg, 31), ib = min((int)sb, 31);
    fr4[i] = sr - ir; fg4[i] = sg - ig; fb4[i] = sb - ib;
    cb4[i] = b * 35937 + ib * 1089 + ig * 33 + ir;
  }

  u32 q[4][4][4];
  const int off[4] = {0, 33, 1089, 1122};
  #pragma unroll
  for (int i = 0; i < 4; i++)
    #pragma unroll
    for (int pr = 0; pr < 4; pr++) {
      const u32* c0 = Fu + (size_t)(cb4[i] + off[pr]) * 2;
      q[i][pr][0] = c0[0]; q[i][pr][1] = c0[1];
      q[i][pr][2] = c0[2]; q[i][pr][3] = c0[3];
    }

  vf4 o0, o1, o2;
  #pragma unroll
  for (int i = 0; i < 4; i++) {
    const float fr = fr4[i], fg = fg4[i], fb = fb4[i];
    #pragma unroll
    for (int c = 0; c < 3; c++) {
      const int k = c >> 1, sh = (c & 1) * 16;
      float v000 = h2f((u16)(q[i][0][k]     >> sh));
      float v001 = h2f((u16)(q[i][0][2 + k] >> sh));
      float v010 = h2f((u16)(q[i][1][k]     >> sh));
      float v011 = h2f((u16)(q[i][1][2 + k] >> sh));
      float v100 = h2f((u16)(q[i][2][k]     >> sh));
      float v101 = h2f((u16)(q[i][2][2 + k] >> sh));
      float v110 = h2f((u16)(q[i][3][k]     >> sh));
      float v111 = h2f((u16)(q[i][3][2 + k] >> sh));
      float c00 = v000 + fr * (v001 - v000);
      float c01 = v010 + fr * (v011 - v010);
      float c10 = v100 + fr * (v101 - v100);
      float c11 = v110 + fr * (v111 - v110);
      float c0 = c00 + fg * (c01 - c00);
      float c1 = c10 + fg * (c11 - c10);
      float v  = c0 + fb * (c1 - c0);
      float xv = (c == 0) ? xr[i] : (c == 1) ? xg[i] : xb[i];
      float o = fminf(fmaxf((1.f - a) * xv + a * v, 0.f), 1.f);
      if (c == 0) o0[i] = o; else if (c == 1) o1[i] = o; else o2[i] = o;
    }
  }
  *(vf4*)(out + (size_t)(b * 3 + 0) * 1048576u + yx0) = o0;
  *(vf4*)(out + (size_t)(b * 3 + 1) * 1048576u + yx0) = o1;
  *(vf4*)(out + (size_t)(b * 3 + 2) * 1048576u + yx0) = o2;
}

// ---------- trilinear apply, fallback 1 px/thread, fp32 SoA ----------
__global__ __launch_bounds__(256) void kapply1(
    const float* __restrict__ x, const float* __restrict__ F,
    float* __restrict__ out)
{
  int p = blockIdx.x * 256 + threadIdx.x;
  if (p == 0) {
    out[OUT_TV] = g_state[GS_ACCS] * (1.f / 418176.f);
    out[OUT_MN] = g_state[GS_ACCS + 1] * (1.f / 418176.f);
  }
  int b = p >> 20, yx = p & 1048575;
  size_t base = (size_t)b * 3145728u + yx;
  float xr = x[base];
  float xg = x[base + 1048576];
  float xb = x[base + 2097152];
  float a = g_state[GS_BLEND + b];
  float sr = fminf(fmaxf(xr, 0.f), 1.f) * 32.f;
  float sg = fminf(fmaxf(xg, 0.f), 1.f) * 32.f;
  float sb = fminf(fmaxf(xb, 0.f), 1.f) * 32.f;
  int ir = min((int)sr, 31), ig = min((int)sg, 31), ib = min((int)sb, 31);
  float fr = sr - ir, fg = sg - ig, fb = sb - ib;
  const float* Fb = F + (size_t)b * 107811u + ib * 1089 + ig * 33 + ir;
  #pragma unroll
  for (int c = 0; c < 3; c++) {
    const float* Fc = Fb + c * 35937;
    float v000 = Fc[0],    v001 = Fc[1];
    float v010 = Fc[33],   v011 = Fc[34];
    float v100 = Fc[1089], v101 = Fc[1090];
    float v110 = Fc[1122], v111 = Fc[1123];
    float c00 = v000 + fr * (v001 - v000);
    float c01 = v010 + fr * (v011 - v010);
    float c10 = v100 + fr * (v101 - v100);
    float c11 = v110 + fr * (v111 - v110);
    float c0 = c00 + fg * (c01 - c00);
    float c1 = c10 + fg * (c11 - c10);
    float v  = c0 + fb * (c1 - c0);
    float xv = (c == 0) ? xr : (c == 1) ? xg : xb;
    float o = fminf(fmaxf((1.f - a) * xv + a * v, 0.f), 1.f);
    out[(size_t)(b * 3 + c) * 1048576u + yx] = o;
  }
}

extern "C" void kernel_launch(void* const* d_in, const int* in_sizes, int n_in,
                              void* d_out, int out_size, void* d_ws, size_t ws_size,
                              hipStream_t stream)
{
  (void)in_sizes; (void)n_in; (void)out_size;
  const float* x    = (const float*)d_in[0];
  const float* luts = (const float*)d_in[1];
  const float* wn_b1 = (const float*)d_in[3];
  const float* wn_b2 = (const float*)d_in[5];
  const float* wn_b3 = (const float*)d_in[7];
  const float* wn_b4 = (const float*)d_in[9];
  const float* wn_fw1 = (const float*)d_in[10], *wn_fb1 = (const float*)d_in[11];
  const float* wn_fw2 = (const float*)d_in[12], *wn_fb2 = (const float*)d_in[13];
  const float* bl_b1 = (const float*)d_in[15];
  const float* bl_b2 = (const float*)d_in[17];
  const float* bl_b3 = (const float*)d_in[19];
  const float* bl_b4 = (const float*)d_in[21];
  const float* bl_fw1 = (const float*)d_in[22], *bl_fb1 = (const float*)d_in[23];
  const float* bl_fw2 = (const float*)d_in[24], *bl_fb2 = (const float*)d_in[25];
  float* out = (float*)d_out;
  const bool hasWs = (ws_size >= 50331648u);

  P2Args p2;
  const float* wsrc[8] = {(const float*)d_in[4],  (const float*)d_in[16],
                          (const float*)d_in[6],  (const float*)d_in[8],
                          (const float*)d_in[18], (const float*)d_in[20],
                          (const float*)d_in[2],  (const float*)d_in[14]};
  const int pI[8]   = {32, 16, 32, 64, 16, 32, 3, 3};
  const int pNTF[8] = {2, 1, 4, 4, 2, 2, 2, 1};
  const int pB[8]   = {WF_WN2, WF_BL2, WF_WN3, WF_WN4, WF_BL3, WF_BL4,
                       WF_WN1, WF_BL1};
  for (int l = 0; l < 8; l++) { p2.w[l] = wsrc[l]; p2.I[l] = pI[l];
                                p2.ntf[l] = pNTF[l]; p2.base[l] = pB[l]; }
  kprep2<<<dim3(354), 256, 0, stream>>>(p2);

  if (hasWs) {
    u16* scrA = (u16*)d_ws;                    // WN h2, 2 batches (33.6 MB)
    u16* scrB = (u16*)d_ws + 16777216;         // WN conv3 out (16.8 MB)
    u16* blh2 = (u16*)out;                     // BL h2, 2 batches (16.8 MB)
    u16* blc3 = (u16*)out + 8388608;           // BL conv3 out (8.4 MB)
    u16* Fa   = (u16*)d_ws;                    // fp16 AoS LUT (post-conv)

    for (int b0 = 0; b0 < 4; b0 += 2) {
      const float* xb = x + (size_t)b0 * 3145728u;
      k12d<<<dim3(32,32,2), 512, 0, stream>>>(xb, wn_b1, wn_b2, bl_b1, bl_b2,
                                              scrA, blh2);
      kc3<<<dim3(16,16,6), 512, 0, stream>>>(scrA, wn_b3, scrB,
                                             blh2, bl_b3, blc3, 4);
      kc4<<<dim3(8,8,6),   512, 0, stream>>>(scrB, wn_b4, GS_FEATWN + b0 * 64,
                                             blc3, bl_b4, GS_FEATBL + b0 * 32, 4);
    }
    kheads<<<2, 256, 0, stream>>>(wn_fw1, wn_fb1, wn_fw2, wn_fb2,
                                  bl_fw1, bl_fb1, bl_fw2, bl_fb2, out + OUT_W3D);

    kfuse<<<1685, 256, 0, stream>>>(luts, out + OUT_FUSED, Fa);
    ktv<<<512, 256, 0, stream>>>(out + OUT_FUSED);
    kapply4<<<4096, 256, 0, stream>>>(x, Fa, out);
  } else {
    // 1-batch passes; all scratch inside d_out (37.7 MB < OUT_FUSED @ 50.3 MB)
    u16* h2wF  = (u16*)out;                 // 16.8 MB
    u16* h2bF  = (u16*)out + 8388608;       //  8.4 MB
    u16* wnc3F = (u16*)out + 12582912;      //  8.4 MB
    u16* blc3F = (u16*)out + 16777216;      //  4.2 MB

    for (int b = 0; b < 4; b++) {
      const float* xb = x + (size_t)b * 3145728u;
      k12d<<<dim3(32,32,1), 512, 0, stream>>>(xb, wn_b1, wn_b2, bl_b1, bl_b2,
                                              h2wF, h2bF);
      kc3<<<dim3(16,16,3), 512, 0, stream>>>(h2wF, wn_b3, wnc3F,
                                             h2bF, bl_b3, blc3F, 2);
      kc4<<<dim3(8,8,3),   512, 0, stream>>>(wnc3F, wn_b4, GS_FEATWN + b * 64,
                                             blc3F, bl_b4, GS_FEATBL + b * 32, 2);
    }
    kheads<<<2, 256, 0, stream>>>(wn_fw1, wn_fb1, wn_fw2, wn_fb2,
                                  bl_fw1, bl_fb1, bl_fw2, bl_fb2, out + OUT_W3D);

    kfuse<<<1685, 256, 0, stream>>>(luts, out + OUT_FUSED, nullptr);
    ktv<<<512, 256, 0, stream>>>(out + OUT_FUSED);
    kapply1<<<16384, 256, 0, stream>>>(x, out + OUT_FUSED, out);
  }
}